// Round 6
// baseline (146716.260 us; speedup 1.0000x reference)
//
#include <hip/hip_runtime.h>

#define HID    512
#define TPB    512
#define NSTEP  60
#define BMI    64

using f32x4 = __attribute__((ext_vector_type(4))) float;
using s16x8 = __attribute__((ext_vector_type(8))) short;

__device__ __forceinline__ unsigned short f2bf(float f) {
    unsigned u = __builtin_bit_cast(unsigned, f);
    u += 0x7fffu + ((u >> 16) & 1u);
    return (unsigned short)(u >> 16);
}
__device__ __forceinline__ float bf2f(unsigned u) {
    return __builtin_bit_cast(float, u << 16);
}
__device__ __forceinline__ float sigm(float x) { return 1.0f / (1.0f + __expf(-x)); }
__device__ __forceinline__ float tanh_(float x) { return 1.0f - 2.0f / (__expf(2.0f * x) + 1.0f); }

__device__ __forceinline__ f32x4 deperm(f32x4 q, int lgr) {
    f32x4 p;
    if (lgr == 0)      { p[0]=q[0]; p[1]=q[1]; p[2]=q[2]; p[3]=q[3]; }
    else if (lgr == 1) { p[0]=q[1]; p[1]=q[0]; p[2]=q[3]; p[3]=q[2]; }
    else if (lgr == 2) { p[0]=q[2]; p[1]=q[3]; p[2]=q[0]; p[3]=q[1]; }
    else               { p[0]=q[3]; p[1]=q[2]; p[2]=q[1]; p[3]=q[0]; }
    return p;
}

// ---------------- weight packing (identical to r3/r4 — verified) ----------------
__global__ void pack_kernel(const float* __restrict__ w_hh0, const float* __restrict__ w_ih1,
                            const float* __restrict__ w_hh1, const float* __restrict__ w_init_h,
                            const float* __restrict__ w_init_c,
                            const float* __restrict__ b_ih0, const float* __restrict__ b_hh0,
                            const float* __restrict__ b_ih1, const float* __restrict__ b_hh1,
                            unsigned short* __restrict__ PW1, unsigned short* __restrict__ PW2,
                            unsigned short* __restrict__ PI,
                            float* __restrict__ b1, float* __restrict__ b2)
{
    int idx = blockIdx.x * 256 + threadIdx.x;
    if (idx < 1048576) {
        int el = idx & 511, fr = idx >> 9;
        int ks = fr & 15, ct = (fr >> 4) & 7, s = fr >> 7;
        int lane = el >> 3, e = el & 7;
        int cl = ct * 16 + (lane & 15);
        int gcol = (cl >> 5) * 512 + s * 32 + (cl & 31);
        int k = ks * 32 + (lane >> 4) * 8 + e;
        PW1[idx] = f2bf(w_hh0[gcol * 512 + k]);
        return;
    }
    int i2 = idx - 1048576;
    if (i2 >= 0 && i2 < 2097152) {
        int el = i2 & 511, fr = i2 >> 9;
        int ks = fr & 31, ct = (fr >> 5) & 7, s = fr >> 8;
        int lane = el >> 3, e = el & 7;
        int cl = ct * 16 + (lane & 15);
        int gcol = (cl >> 5) * 512 + s * 32 + (cl & 31);
        int kk = (ks & 15) * 32 + (lane >> 4) * 8 + e;
        float v = (ks < 16) ? w_ih1[gcol * 512 + kk] : w_hh1[gcol * 512 + kk];
        PW2[i2] = f2bf(v);
        return;
    }
    int i3 = idx - (1048576 + 2097152);
    if (i3 >= 0 && i3 < 524288) {
        int el = i3 & 511, fr = i3 >> 9;
        int ks = fr & 15, tile = fr >> 4;
        int s = tile >> 5, c = tile & 31;
        int lane = el >> 3, e = el & 7;
        int n = c * 16 + (lane & 15);
        int k = ks * 32 + (lane >> 4) * 8 + e;
        float v = s ? w_init_c[n * 512 + k] : w_init_h[n * 512 + k];
        PI[i3] = f2bf(v);
        return;
    }
    int i4 = idx - (1048576 + 2097152 + 524288);
    if (i4 >= 0 && i4 < 2048) b1[i4] = b_ih0[i4] + b_hh0[i4];
    else if (i4 >= 2048 && i4 < 4096) b2[i4 - 2048] = b_ih1[i4 - 2048] + b_hh1[i4 - 2048];
}

// ---------------- init (r4 version, interleaved [m][512] state) ----------------
__global__ __launch_bounds__(TPB, 2) void init_kernel(
    const float* __restrict__ hin, const unsigned short* __restrict__ PI,
    const float* __restrict__ b_init_h, const float* __restrict__ b_init_c,
    unsigned short* __restrict__ h1s, unsigned short* __restrict__ h2s,
    unsigned short* __restrict__ c1s, unsigned short* __restrict__ c2s)
{
    __shared__ unsigned short bufA[BMI * HID];
    const int tid = threadIdx.x, lane = tid & 63, wave = tid >> 6;
    const int m0 = blockIdx.x * BMI;
    const int l15 = lane & 15, lg = lane >> 4;
    const int swz = (lane & 7) << 4;

    for (int j = 0; j < 16; ++j) {
        int e = tid * 4 + j * 2048;
        int row = e >> 9, col = e & 511;
        float4 v = *(const float4*)(hin + (size_t)(m0 + row) * HID + col);
        ushort4 w;
        w.x = f2bf(v.x); w.y = f2bf(v.y); w.z = f2bf(v.z); w.w = f2bf(v.w);
        int L = (row * 1024 + col * 2) ^ ((row & 7) << 4);
        *(ushort4*)((char*)bufA + L) = w;
    }
    __syncthreads();

    #pragma unroll 1
    for (int cc = 0; cc < 4; ++cc) {
        int c = wave * 4 + cc;
        int nc = c * 16 + l15;
        f32x4 acc[4][2];
        #pragma unroll
        for (int rt = 0; rt < 4; ++rt)
            #pragma unroll
            for (int s = 0; s < 2; ++s)
                #pragma unroll
                for (int r = 0; r < 4; ++r) acc[rt][s][r] = 0.0f;

        #pragma unroll
        for (int ks = 0; ks < 16; ++ks) {
            s16x8 a[4];
            #pragma unroll
            for (int rt = 0; rt < 4; ++rt) {
                int ao = (rt * 16 + l15) * 1024 + ((ks * 64 + lg * 16) ^ swz);
                a[rt] = *(const s16x8*)((const char*)bufA + ao);
            }
            #pragma unroll
            for (int s = 0; s < 2; ++s) {
                s16x8 b = ((const s16x8*)PI)[((s * 32 + c) * 16 + ks) * 64 + lane];
                #pragma unroll
                for (int rt = 0; rt < 4; ++rt)
                    acc[rt][s] = __builtin_amdgcn_mfma_f32_16x16x32_bf16(a[rt], b, acc[rt][s], 0, 0, 0);
            }
        }
        float bh = b_init_h[nc], bc = b_init_c[nc];
        #pragma unroll
        for (int rt = 0; rt < 4; ++rt)
            #pragma unroll
            for (int r = 0; r < 4; ++r) {
                int m = m0 + rt * 16 + lg * 4 + r;
                float hv = acc[rt][0][r] + bh;
                float cv = acc[rt][1][r] + bc;
                unsigned short hb = f2bf(hv);
                size_t o = (size_t)m * HID + nc;
                h1s[o] = hb; h2s[o] = hb;
                c1s[o] = f2bf(cv); c2s[o] = f2bf(cv);
            }
    }
}

// ---------------- layer-1: 512 blocks (32 groups x 16 slices), CHUNK=16, 2 blk/CU ----------------
// waves: cg=w>>1 (4) x kh=w&1 (2); each wave: 2 ct-tiles, K-half. gl merged via ds_add_f32.
__global__ __launch_bounds__(512, 4) void l1_kernel(
    const unsigned short* __restrict__ h1R, unsigned short* __restrict__ h1W,
    unsigned short* __restrict__ c1s, const float* __restrict__ pp,
    float* __restrict__ outp, const unsigned short* __restrict__ PW1,
    const float* __restrict__ b1, const float* __restrict__ w_ih0,
    const float* __restrict__ b_out, int t)
{
    __shared__ __align__(16) unsigned short Ab[8192];   // 16 KB: [ks16][lg4][l15 16][16B]
    __shared__ __align__(16) float gl[2][1028];         // 8.2 KB gate accumulator
    __shared__ __align__(16) float xls[2048];           // 8 KB: x for 1024 rows

    const int tid = threadIdx.x, lane = tid & 63, w = tid >> 6;
    const int b = blockIdx.x;
    const int g = (b & 7) * 4 + (b >> 7);     // 1024-row group; XCD = g>>2 = b&7
    const int s = (b >> 3) & 15;
    const int m0 = g * 1024;
    const int l15 = lane & 15, lg = lane >> 4;
    const int cg = w >> 1, kh = w & 1;

    // zero gl
    for (int i = tid; i < 2056; i += 512) ((float*)gl)[i] = 0.f;

    // B fragments: ct = cg*2+j, ks = kh*8+ksl  (64 VGPR)
    s16x8 bw[2][8];
    #pragma unroll
    for (int j = 0; j < 2; ++j)
        #pragma unroll
        for (int ksl = 0; ksl < 8; ++ksl)
            bw[j][ksl] = ((const s16x8*)PW1)[(((s * 8 + cg * 2 + j) * 16) + kh * 8 + ksl) * 64 + lane];

    // epilogue role: row erow (0..15 within chunk), unit eu (0..31)
    const int erow = tid >> 5, eu = tid & 31;
    const int lgr = erow >> 2;                 // wave-uniform (= tid>>7)
    float b1v[4], wiA[4], wiB[4];
    #pragma unroll
    for (int q = 0; q < 4; ++q) {
        int gcol = q * 512 + s * 32 + eu;
        b1v[q] = b1[gcol];
        wiA[q] = w_ih0[gcol * 2 + 0];
        wiB[q] = w_ih0[gcol * 2 + 1];
    }
    const float bo0 = b_out[0], bo1 = b_out[1];

    // ---- inter-step: reduce prev partials -> xls; write out[:, t-1] ----
    if (t == 0) {
        #pragma unroll
        for (int i = 0; i < 4; ++i) xls[tid * 4 + i] = 0.0f;
    } else {
        f32x4 s0 = {0.f, 0.f, 0.f, 0.f};
        #pragma unroll 1
        for (int ss = 0; ss < 16; ++ss)
            s0 += *(const f32x4*)(pp + (((size_t)((g >> 1) * 16 + ss)) << 12)
                                  + (g & 1) * 2048 + tid * 4);
        s0[0] += bo0; s0[1] += bo1; s0[2] += bo0; s0[3] += bo1;
        *(f32x4*)(xls + tid * 4) = s0;
        if (s == 0) {
            float* ob = outp + (size_t)(m0 + tid * 2) * (2 * NSTEP) + (t - 1) * 2;
            *(float2*)(ob)             = make_float2(s0[0], s0[1]);
            *(float2*)(ob + 2 * NSTEP) = make_float2(s0[2], s0[3]);
        }
    }

    // staging decompose: LDS byte = p*8192 + tid*16 -> ks = p*8 + (tid>>6), lg' = (tid>>4)&3, row = tid&15
    const int st_row = tid & 15, st_lg = (tid >> 4) & 3, st_ks = tid >> 6;

    // prologue: stage chunk 0
    uint4 nv[2];
    #pragma unroll
    for (int p = 0; p < 2; ++p)
        nv[p] = *(const uint4*)(h1R + (size_t)(m0 + st_row) * HID + (p * 8 + st_ks) * 32 + st_lg * 8);
    #pragma unroll
    for (int p = 0; p < 2; ++p)
        *(uint4*)((char*)Ab + p * 8192 + tid * 16) = nv[p];

    #pragma unroll 1
    for (int ch = 0; ch < 64; ++ch) {
        __syncthreads();   // (a) Ab[ch] + xls + gl-zero ready

        if (ch < 63) {
            #pragma unroll
            for (int p = 0; p < 2; ++p)
                nv[p] = *(const uint4*)(h1R + (size_t)(m0 + (ch + 1) * 16 + st_row) * HID
                                        + (p * 8 + st_ks) * 32 + st_lg * 8);
        }
        // c-prefetch for this chunk's epilogue
        unsigned short cw = c1s[(size_t)(m0 + ch * 16 + erow) * HID + s * 32 + eu];

        // GEMM: 16 rows x (2 ct tiles) over K-half kh
        f32x4 acc[2];
        #pragma unroll
        for (int j = 0; j < 2; ++j) { acc[j][0]=0.f; acc[j][1]=0.f; acc[j][2]=0.f; acc[j][3]=0.f; }
        #pragma unroll
        for (int ksl = 0; ksl < 8; ++ksl) {
            s16x8 a = *(const s16x8*)((const char*)Ab + (kh * 8 + ksl) * 1024 + lane * 16);
            #pragma unroll
            for (int j = 0; j < 2; ++j)
                acc[j] = __builtin_amdgcn_mfma_f32_16x16x32_bf16(a, bw[j][ksl], acc[j], 0, 0, 0);
        }
        // merge via LDS float atomics (2 kh-waves contend per address)
        #pragma unroll
        for (int j = 0; j < 2; ++j) {
            int col = (cg * 2 + j) * 16 + l15;
            int u = col & 31, gate = col >> 5;
            #pragma unroll
            for (int r = 0; r < 4; ++r)
                atomicAdd(&gl[u & 1][(lg * 4 + r) * 64 + (u >> 1) * 4 + (gate ^ lg)], acc[j][r]);
        }
        __syncthreads();   // (b) gl complete; Ab reads done

        if (ch < 63) {
            #pragma unroll
            for (int p = 0; p < 2; ++p)
                *(uint4*)((char*)Ab + p * 8192 + tid * 16) = nv[p];
        }

        // epilogue: 1 unit/thread
        {
            int mloc = ch * 16 + erow;
            float x0 = xls[mloc * 2 + 0], x1 = xls[mloc * 2 + 1];
            float* gp = &gl[eu & 1][erow * 64 + (eu >> 1) * 4];
            f32x4 q = *(const f32x4*)gp;
            *(f32x4*)gp = (f32x4){0.f, 0.f, 0.f, 0.f};   // re-zero for next chunk
            q = deperm(q, lgr);
            float iv = sigm(q[0] + b1v[0] + x0 * wiA[0] + x1 * wiB[0]);
            float fv = sigm(q[1] + b1v[1] + x0 * wiA[1] + x1 * wiB[1]);
            float gv = tanh_(q[2] + b1v[2] + x0 * wiA[2] + x1 * wiB[2]);
            float ov = sigm(q[3] + b1v[3] + x0 * wiA[3] + x1 * wiB[3]);
            float cold = bf2f(cw);
            float cn = fv * cold + iv * gv;
            float hn = ov * tanh_(cn);
            size_t cix = (size_t)(m0 + mloc) * HID + s * 32 + eu;
            c1s[cix] = f2bf(cn);
            h1W[cix] = f2bf(hn);
        }
    }
}

// ---------------- layer-2: 256 blocks (16 groups x 16 slices), CHUNK=32, K=1024 ----------------
// waves: cg=w&1 (2) x kq=w>>1 (4). gl merged via ds_add_f32 (2 syncs/chunk, was 3).
__global__ __launch_bounds__(512, 2) void l2_kernel(
    const unsigned short* __restrict__ h1C, const unsigned short* __restrict__ h2R,
    unsigned short* __restrict__ h2W, unsigned short* __restrict__ c2s,
    float* __restrict__ pp,
    const unsigned short* __restrict__ PW2, const float* __restrict__ b2,
    const float* __restrict__ w_out)
{
    __shared__ __align__(16) unsigned short Ab[32768];   // 64 KB: [ks32][rh2][lg4][l15 16][16B]
    __shared__ __align__(16) float gl[2][2052];          // 16.4 KB gate accumulator

    const int tid = threadIdx.x, lane = tid & 63, w = tid >> 6;
    const int b = blockIdx.x;
    const int g = 2 * (b & 7) + (b >> 7);
    const int s = (b >> 3) & 15;
    const int m0 = g * 2048;
    const int l15 = lane & 15, lg = lane >> 4;
    const int cg = w & 1, kq = w >> 1;

    for (int i = tid; i < 4104; i += 512) ((float*)gl)[i] = 0.f;

    s16x8 bw[4][8];
    #pragma unroll
    for (int j = 0; j < 4; ++j)
        #pragma unroll
        for (int ksl = 0; ksl < 8; ++ksl)
            bw[j][ksl] = ((const s16x8*)PW2)[(((s * 8 + cg * 4 + j) * 32) + kq * 8 + ksl) * 64 + lane];

    const int erow = tid >> 4, ejp = tid & 15;
    const int lgr = w & 3;
    float b2v[8];
    #pragma unroll
    for (int q = 0; q < 8; ++q) {
        int dj = q & 1, gq = q >> 1;
        b2v[q] = b2[gq * 512 + s * 32 + ejp * 2 + dj];
    }
    float woA0 = w_out[s * 32 + ejp * 2], woA1 = w_out[s * 32 + ejp * 2 + 1];
    float woB0 = w_out[512 + s * 32 + ejp * 2], woB1 = w_out[512 + s * 32 + ejp * 2 + 1];

    const int st_l15 = tid & 15, st_lg = (tid >> 4) & 3, st_rh = (tid >> 6) & 1, st_ks = tid >> 7;
    const int st_row = st_rh * 16 + st_l15;

    uint4 nv[8];
    #pragma unroll
    for (int p = 0; p < 8; ++p) {
        int ks = p * 4 + st_ks;
        const unsigned short* src = (ks < 16) ? h1C : h2R;
        int kel = (ks < 16) ? ks : (ks - 16);
        nv[p] = *(const uint4*)(src + (size_t)(m0 + st_row) * HID + kel * 32 + st_lg * 8);
    }
    #pragma unroll
    for (int p = 0; p < 8; ++p)
        *(uint4*)((char*)Ab + p * 8192 + tid * 16) = nv[p];

    #pragma unroll 1
    for (int ch = 0; ch < 64; ++ch) {
        __syncthreads();   // (a) Ab ready; gl zeroed

        if (ch < 63) {
            #pragma unroll
            for (int p = 0; p < 8; ++p) {
                int ks = p * 4 + st_ks;
                const unsigned short* src = (ks < 16) ? h1C : h2R;
                int kel = (ks < 16) ? ks : (ks - 16);
                nv[p] = *(const uint4*)(src + (size_t)(m0 + (ch + 1) * 32 + st_row) * HID + kel * 32 + st_lg * 8);
            }
        }
        // c-prefetch (2 units)
        unsigned cw = *(const unsigned*)(c2s + (size_t)(m0 + ch * 32 + erow) * HID + s * 32 + ejp * 2);

        f32x4 acc[2][4];
        #pragma unroll
        for (int rh = 0; rh < 2; ++rh)
            #pragma unroll
            for (int j = 0; j < 4; ++j) { acc[rh][j][0]=0.f; acc[rh][j][1]=0.f; acc[rh][j][2]=0.f; acc[rh][j][3]=0.f; }
        #pragma unroll
        for (int ksl = 0; ksl < 8; ++ksl) {
            int ks = kq * 8 + ksl;
            s16x8 a0 = *(const s16x8*)((const char*)Ab + ks * 2048 + lane * 16);
            s16x8 a1 = *(const s16x8*)((const char*)Ab + ks * 2048 + 1024 + lane * 16);
            #pragma unroll
            for (int j = 0; j < 4; ++j) {
                acc[0][j] = __builtin_amdgcn_mfma_f32_16x16x32_bf16(a0, bw[j][ksl], acc[0][j], 0, 0, 0);
                acc[1][j] = __builtin_amdgcn_mfma_f32_16x16x32_bf16(a1, bw[j][ksl], acc[1][j], 0, 0, 0);
            }
        }
        #pragma unroll
        for (int j = 0; j < 4; ++j) {
            int col = (cg * 4 + j) * 16 + l15;
            int u = col & 31, gate = col >> 5;
            #pragma unroll
            for (int rh = 0; rh < 2; ++rh)
                #pragma unroll
                for (int r = 0; r < 4; ++r)
                    atomicAdd(&gl[u & 1][(rh * 16 + lg * 4 + r) * 64 + (u >> 1) * 4 + (gate ^ lg)],
                              acc[rh][j][r]);
        }
        __syncthreads();   // (b) gl complete; Ab reads done

        if (ch < 63) {
            #pragma unroll
            for (int p = 0; p < 8; ++p)
                *(uint4*)((char*)Ab + p * 8192 + tid * 16) = nv[p];
        }

        {
            int mloc = ch * 32 + erow;
            int gbase = erow * 64 + ejp * 4;
            float* gpa = &gl[0][gbase];
            float* gpb = &gl[1][gbase];
            f32x4 qa = *(const f32x4*)gpa;
            f32x4 qb = *(const f32x4*)gpb;
            *(f32x4*)gpa = (f32x4){0.f, 0.f, 0.f, 0.f};
            *(f32x4*)gpb = (f32x4){0.f, 0.f, 0.f, 0.f};
            qa = deperm(qa, lgr); qb = deperm(qb, lgr);

            float cold0 = bf2f(cw & 0xffffu), cold1 = bf2f(cw >> 16);
            float i0 = sigm(qa[0] + b2v[0]);
            float f0 = sigm(qa[1] + b2v[2]);
            float g0 = tanh_(qa[2] + b2v[4]);
            float o0 = sigm(qa[3] + b2v[6]);
            float cn0 = f0 * cold0 + i0 * g0;
            float hn0 = o0 * tanh_(cn0);
            float i1 = sigm(qb[0] + b2v[1]);
            float f1 = sigm(qb[1] + b2v[3]);
            float g1 = tanh_(qb[2] + b2v[5]);
            float o1 = sigm(qb[3] + b2v[7]);
            float cn1 = f1 * cold1 + i1 * g1;
            float hn1 = o1 * tanh_(cn1);
            size_t cix = (size_t)(m0 + mloc) * HID + s * 32 + ejp * 2;
            *(unsigned*)(c2s + cix) = (unsigned)f2bf(cn0) | ((unsigned)f2bf(cn1) << 16);
            *(unsigned*)(h2W + cix) = (unsigned)f2bf(hn0) | ((unsigned)f2bf(hn1) << 16);

            float p0 = hn0 * woA0 + hn1 * woA1;
            float p1 = hn0 * woB0 + hn1 * woB1;
            #pragma unroll
            for (int d = 1; d < 16; d <<= 1) {
                p0 += __shfl_xor(p0, d, 16);
                p1 += __shfl_xor(p1, d, 16);
            }
            if (ejp == 0)
                *(float2*)(pp + (((size_t)(g * 16 + s)) << 12) + (size_t)mloc * 2)
                    = make_float2(p0, p1);
        }
    }
}

// ---------------- final-step output ----------------
__global__ void tail_kernel(const float* __restrict__ pp, const float* __restrict__ b_out,
                            float* __restrict__ outp)
{
    int i = blockIdx.x * 256 + threadIdx.x;
    if (i < 65536) {
        int m = i >> 1, j = i & 1;
        int g = m >> 11;
        int idx = (m & 2047) * 2 + j;
        float sum = b_out[j];
        #pragma unroll 1
        for (int s = 0; s < 16; ++s)
            sum += pp[(((size_t)(g * 16 + s)) << 12) + idx];
        outp[(size_t)m * (2 * NSTEP) + (NSTEP - 1) * 2 + j] = sum;
    }
}

extern "C" void kernel_launch(void* const* d_in, const int* in_sizes, int n_in,
                              void* d_out, int out_size, void* d_ws, size_t ws_size,
                              hipStream_t stream)
{
    (void)in_sizes; (void)n_in; (void)out_size; (void)ws_size;
    const float* h        = (const float*)d_in[0];
    const float* w_init_h = (const float*)d_in[1];
    const float* b_init_h = (const float*)d_in[2];
    const float* w_init_c = (const float*)d_in[3];
    const float* b_init_c = (const float*)d_in[4];
    const float* w_ih0    = (const float*)d_in[5];
    const float* w_hh0    = (const float*)d_in[6];
    const float* b_ih0    = (const float*)d_in[7];
    const float* b_hh0    = (const float*)d_in[8];
    const float* w_ih1    = (const float*)d_in[9];
    const float* w_hh1    = (const float*)d_in[10];
    const float* b_ih1    = (const float*)d_in[11];
    const float* b_hh1    = (const float*)d_in[12];
    const float* w_out    = (const float*)d_in[13];
    const float* b_out    = (const float*)d_in[14];
    float* out = (float*)d_out;

    char* ws = (char*)d_ws;
    unsigned short* h1s[2] = { (unsigned short*)(ws + 0),
                               (unsigned short*)(ws + 33554432) };
    unsigned short* h2s[2] = { (unsigned short*)(ws + 67108864),
                               (unsigned short*)(ws + 100663296) };
    unsigned short* c1s = (unsigned short*)(ws + 134217728);
    unsigned short* c2s = (unsigned short*)(ws + 167772160);
    float* pp           = (float*)(ws + 201326592);   // 4 MB
    unsigned short* PW1 = (unsigned short*)(ws + 205520896);
    unsigned short* PW2 = (unsigned short*)(ws + 207618048);
    unsigned short* PI  = (unsigned short*)(ws + 211812352);
    float* b1 = (float*)(ws + 212860928);
    float* b2 = (float*)(ws + 212869120);

    pack_kernel<<<14352, 256, 0, stream>>>(w_hh0, w_ih1, w_hh1, w_init_h, w_init_c,
                                           b_ih0, b_hh0, b_ih1, b_hh1, PW1, PW2, PI, b1, b2);
    init_kernel<<<32768 / BMI, TPB, 0, stream>>>(h, PI, b_init_h, b_init_c,
                                                 h1s[1], h2s[1], c1s, c2s);
    for (int t = 0; t < NSTEP; ++t) {
        const unsigned short* h1R = h1s[(t + 1) & 1];
        unsigned short* h1W = h1s[t & 1];
        const unsigned short* h2R = h2s[(t + 1) & 1];
        unsigned short* h2W = h2s[t & 1];
        l1_kernel<<<512, 512, 0, stream>>>(h1R, h1W, c1s, pp, out, PW1, b1, w_ih0, b_out, t);
        l2_kernel<<<256, 512, 0, stream>>>(h1W, h2R, h2W, c2s, pp, PW2, b2, w_out);
    }
    tail_kernel<<<256, 256, 0, stream>>>(pp, b_out, out);
}

// Round 7
// 58959.998 us; speedup vs baseline: 2.4884x; 2.4884x over previous
//
#include <hip/hip_runtime.h>

#define HID    512
#define TPB    512
#define NSTEP  60
#define BMI    64

using f32x4 = __attribute__((ext_vector_type(4))) float;
using s16x8 = __attribute__((ext_vector_type(8))) short;

__device__ __forceinline__ unsigned short f2bf(float f) {
    unsigned u = __builtin_bit_cast(unsigned, f);
    u += 0x7fffu + ((u >> 16) & 1u);
    return (unsigned short)(u >> 16);
}
__device__ __forceinline__ float bf2f(unsigned u) {
    return __builtin_bit_cast(float, u << 16);
}
__device__ __forceinline__ float sigm(float x) { return 1.0f / (1.0f + __expf(-x)); }
__device__ __forceinline__ float tanh_(float x) { return 1.0f - 2.0f / (__expf(2.0f * x) + 1.0f); }

__device__ __forceinline__ f32x4 deperm(f32x4 q, int lgr) {
    f32x4 p;
    if (lgr == 0)      { p[0]=q[0]; p[1]=q[1]; p[2]=q[2]; p[3]=q[3]; }
    else if (lgr == 1) { p[0]=q[1]; p[1]=q[0]; p[2]=q[3]; p[3]=q[2]; }
    else if (lgr == 2) { p[0]=q[2]; p[1]=q[3]; p[2]=q[0]; p[3]=q[1]; }
    else               { p[0]=q[3]; p[1]=q[2]; p[2]=q[1]; p[3]=q[0]; }
    return p;
}

// ---------------- weight packing (identical to r3/r4 — verified) ----------------
__global__ void pack_kernel(const float* __restrict__ w_hh0, const float* __restrict__ w_ih1,
                            const float* __restrict__ w_hh1, const float* __restrict__ w_init_h,
                            const float* __restrict__ w_init_c,
                            const float* __restrict__ b_ih0, const float* __restrict__ b_hh0,
                            const float* __restrict__ b_ih1, const float* __restrict__ b_hh1,
                            unsigned short* __restrict__ PW1, unsigned short* __restrict__ PW2,
                            unsigned short* __restrict__ PI,
                            float* __restrict__ b1, float* __restrict__ b2)
{
    int idx = blockIdx.x * 256 + threadIdx.x;
    if (idx < 1048576) {
        int el = idx & 511, fr = idx >> 9;
        int ks = fr & 15, ct = (fr >> 4) & 7, s = fr >> 7;
        int lane = el >> 3, e = el & 7;
        int cl = ct * 16 + (lane & 15);
        int gcol = (cl >> 5) * 512 + s * 32 + (cl & 31);
        int k = ks * 32 + (lane >> 4) * 8 + e;
        PW1[idx] = f2bf(w_hh0[gcol * 512 + k]);
        return;
    }
    int i2 = idx - 1048576;
    if (i2 >= 0 && i2 < 2097152) {
        int el = i2 & 511, fr = i2 >> 9;
        int ks = fr & 31, ct = (fr >> 5) & 7, s = fr >> 8;
        int lane = el >> 3, e = el & 7;
        int cl = ct * 16 + (lane & 15);
        int gcol = (cl >> 5) * 512 + s * 32 + (cl & 31);
        int kk = (ks & 15) * 32 + (lane >> 4) * 8 + e;
        float v = (ks < 16) ? w_ih1[gcol * 512 + kk] : w_hh1[gcol * 512 + kk];
        PW2[i2] = f2bf(v);
        return;
    }
    int i3 = idx - (1048576 + 2097152);
    if (i3 >= 0 && i3 < 524288) {
        int el = i3 & 511, fr = i3 >> 9;
        int ks = fr & 15, tile = fr >> 4;
        int s = tile >> 5, c = tile & 31;
        int lane = el >> 3, e = el & 7;
        int n = c * 16 + (lane & 15);
        int k = ks * 32 + (lane >> 4) * 8 + e;
        float v = s ? w_init_c[n * 512 + k] : w_init_h[n * 512 + k];
        PI[i3] = f2bf(v);
        return;
    }
    int i4 = idx - (1048576 + 2097152 + 524288);
    if (i4 >= 0 && i4 < 2048) b1[i4] = b_ih0[i4] + b_hh0[i4];
    else if (i4 >= 2048 && i4 < 4096) b2[i4 - 2048] = b_ih1[i4 - 2048] + b_hh1[i4 - 2048];
}

// ---------------- init: BLOCK-MAJOR state [g*16+s][2048][32] (verified in r5) ----------------
__global__ __launch_bounds__(TPB, 2) void init_kernel(
    const float* __restrict__ hin, const unsigned short* __restrict__ PI,
    const float* __restrict__ b_init_h, const float* __restrict__ b_init_c,
    unsigned short* __restrict__ h1s, unsigned short* __restrict__ h2s,
    unsigned short* __restrict__ c1s, unsigned short* __restrict__ c2s)
{
    __shared__ unsigned short bufA[BMI * HID];
    const int tid = threadIdx.x, lane = tid & 63, wave = tid >> 6;
    const int m0 = blockIdx.x * BMI;
    const int l15 = lane & 15, lg = lane >> 4;
    const int swz = (lane & 7) << 4;

    for (int j = 0; j < 16; ++j) {
        int e = tid * 4 + j * 2048;
        int row = e >> 9, col = e & 511;
        float4 v = *(const float4*)(hin + (size_t)(m0 + row) * HID + col);
        ushort4 w;
        w.x = f2bf(v.x); w.y = f2bf(v.y); w.z = f2bf(v.z); w.w = f2bf(v.w);
        int L = (row * 1024 + col * 2) ^ ((row & 7) << 4);
        *(ushort4*)((char*)bufA + L) = w;
    }
    __syncthreads();

    #pragma unroll 1
    for (int cc = 0; cc < 4; ++cc) {
        int c = wave * 4 + cc;
        int nc = c * 16 + l15;
        f32x4 acc[4][2];
        #pragma unroll
        for (int rt = 0; rt < 4; ++rt)
            #pragma unroll
            for (int s = 0; s < 2; ++s)
                #pragma unroll
                for (int r = 0; r < 4; ++r) acc[rt][s][r] = 0.0f;

        #pragma unroll
        for (int ks = 0; ks < 16; ++ks) {
            s16x8 a[4];
            #pragma unroll
            for (int rt = 0; rt < 4; ++rt) {
                int ao = (rt * 16 + l15) * 1024 + ((ks * 64 + lg * 16) ^ swz);
                a[rt] = *(const s16x8*)((const char*)bufA + ao);
            }
            #pragma unroll
            for (int s = 0; s < 2; ++s) {
                s16x8 b = ((const s16x8*)PI)[((s * 32 + c) * 16 + ks) * 64 + lane];
                #pragma unroll
                for (int rt = 0; rt < 4; ++rt)
                    acc[rt][s] = __builtin_amdgcn_mfma_f32_16x16x32_bf16(a[rt], b, acc[rt][s], 0, 0, 0);
            }
        }
        float bh = b_init_h[nc], bc = b_init_c[nc];
        int sl = nc >> 5, ul = nc & 31;
        #pragma unroll
        for (int rt = 0; rt < 4; ++rt)
            #pragma unroll
            for (int r = 0; r < 4; ++r) {
                int m = m0 + rt * 16 + lg * 4 + r;
                int gg = m >> 11, lr = m & 2047;
                float hv = acc[rt][0][r] + bh;
                float cv = acc[rt][1][r] + bc;
                unsigned short hb = f2bf(hv);
                size_t o = ((size_t)(gg * 16 + sl) * 2048 + lr) * 32 + ul;
                h1s[o] = hb; h2s[o] = hb;
                c1s[o] = f2bf(cv); c2s[o] = f2bf(cv);
            }
    }
}

// ---------------- layer-1 (r4 structure + block-major + dist-2 prefetch) ----------------
__global__ __launch_bounds__(TPB, 2) void l1_kernel(
    const unsigned short* __restrict__ h1R, unsigned short* __restrict__ h1W,
    unsigned short* __restrict__ c1s, const float* __restrict__ pp,
    float* __restrict__ outp, const unsigned short* __restrict__ PW1,
    const float* __restrict__ b1, const float* __restrict__ w_ih0,
    const float* __restrict__ b_out, int t)
{
    __shared__ __align__(16) unsigned short Ab[16384];     // 32 KB: [ks16][rh2][lg4][l15][16B]
    __shared__ __align__(16) float gl[2][2][2048];         // 32 KB
    __shared__ __align__(16) float xls[4160];              // 16.25 KB

    const int tid = threadIdx.x, lane = tid & 63, w = tid >> 6;
    const int b = blockIdx.x;
    const int g = 2 * (b & 7) + (b >> 7);
    const int s = (b >> 3) & 15;
    const int l15 = lane & 15, lg = lane >> 4;
    const int cg = w & 1, kh = (w >> 1) & 1, rha = w >> 2;
    const size_t gB = (size_t)g * 16;
    const size_t blkOff = (gB + s) * 2048 * 32;

    s16x8 bw[4][8];
    #pragma unroll
    for (int j = 0; j < 4; ++j)
        #pragma unroll
        for (int ksl = 0; ksl < 8; ++ksl)
            bw[j][ksl] = ((const s16x8*)PW1)[(((s * 8 + cg * 4 + j) * 16) + kh * 8 + ksl) * 64 + lane];

    const int erow = tid >> 4, ejp = tid & 15;
    const int lgr = w & 3;
    float b1v[8], wiA[8], wiB[8];
    #pragma unroll
    for (int q = 0; q < 8; ++q) {
        int dj = q & 1, gq = q >> 1;
        int gcol = gq * 512 + s * 32 + ejp * 2 + dj;
        b1v[q] = b1[gcol];
        wiA[q] = w_ih0[gcol * 2 + 0];
        wiB[q] = w_ih0[gcol * 2 + 1];
    }
    float bo0 = b_out[0], bo1 = b_out[1];

    // ---- reduce prev-step partials -> xls; write out[:, t-1] ----
    if (t == 0) {
        #pragma unroll
        for (int i = 0; i < 8; ++i) xls[tid * 8 + i] = 0.0f;
    } else {
        f32x4 s0 = {0.f,0.f,0.f,0.f}, s1 = {0.f,0.f,0.f,0.f};
        #pragma unroll 1
        for (int ss = 0; ss < 16; ++ss) {
            const float* p = pp + (((size_t)(g * 16 + ss)) << 12) + tid * 8;
            s0 += *(const f32x4*)p;
            s1 += *(const f32x4*)(p + 4);
        }
        s0[0] += bo0; s0[1] += bo1; s0[2] += bo0; s0[3] += bo1;
        s1[0] += bo0; s1[1] += bo1; s1[2] += bo0; s1[3] += bo1;
        *(f32x4*)(xls + tid * 8) = s0;
        *(f32x4*)(xls + tid * 8 + 4) = s1;
        if (s == 0) {
            float* ob = outp + (size_t)(g * 2048 + tid * 4) * (2 * NSTEP) + (t - 1) * 2;
            *(float2*)(ob)             = make_float2(s0[0], s0[1]);
            *(float2*)(ob + 2 * NSTEP) = make_float2(s0[2], s0[3]);
            *(float2*)(ob + 4 * NSTEP) = make_float2(s1[0], s1[1]);
            *(float2*)(ob + 6 * NSTEP) = make_float2(s1[2], s1[3]);
        }
    }

    // staging decompose: byte = p*8192 + tid*16 -> ks = p*4 + (tid>>7)
    const int st_ks4 = tid >> 7;
    const int st_row = ((tid >> 6) & 1) * 16 + (tid & 15);
    const int st_lg  = (tid >> 4) & 3;

    // prologue: stage chunk 0; issue chunk 1
    uint4 nvW[4], nvF[4];
    #pragma unroll
    for (int p = 0; p < 4; ++p)
        nvF[p] = *(const uint4*)(h1R + ((gB + (p * 4 + st_ks4)) * 2048 + st_row) * 32 + st_lg * 8);
    #pragma unroll
    for (int p = 0; p < 4; ++p)
        *(uint4*)((char*)Ab + p * 8192 + tid * 16) = nvF[p];
    #pragma unroll
    for (int p = 0; p < 4; ++p)
        nvW[p] = *(const uint4*)(h1R + ((gB + (p * 4 + st_ks4)) * 2048 + 32 + st_row) * 32 + st_lg * 8);

    #pragma unroll 1
    for (int ch = 0; ch < 64; ++ch) {
        __syncthreads();   // (a) Ab[ch] + xls ready; prev epilogue done with gl

        if (ch < 62) {     // issue loads for ch+2
            #pragma unroll
            for (int p = 0; p < 4; ++p)
                nvF[p] = *(const uint4*)(h1R + ((gB + (p * 4 + st_ks4)) * 2048
                                         + (ch + 2) * 32 + st_row) * 32 + st_lg * 8);
        }
        // c prefetch for this chunk's epilogue
        unsigned cw = *(const unsigned*)(c1s + blkOff + (size_t)(ch * 32 + erow) * 32 + ejp * 2);

        f32x4 acc[4];
        #pragma unroll
        for (int j = 0; j < 4; ++j) { acc[j][0]=0.f; acc[j][1]=0.f; acc[j][2]=0.f; acc[j][3]=0.f; }
        #pragma unroll
        for (int ksl = 0; ksl < 8; ++ksl) {
            int ks = kh * 8 + ksl;
            s16x8 a = *(const s16x8*)((const char*)Ab + ks * 2048 + rha * 1024 + lane * 16);
            #pragma unroll
            for (int j = 0; j < 4; ++j)
                acc[j] = __builtin_amdgcn_mfma_f32_16x16x32_bf16(a, bw[j][ksl], acc[j], 0, 0, 0);
        }
        #pragma unroll
        for (int j = 0; j < 4; ++j) {
            int col = (cg * 4 + j) * 16 + l15;
            int u = col & 31, gate = col >> 5;
            float* dst = &gl[kh][u & 1][(u >> 1) * 4 + (gate ^ lg)];
            #pragma unroll
            for (int r = 0; r < 4; ++r)
                dst[(rha * 16 + lg * 4 + r) * 64] = acc[j][r];
        }
        __syncthreads();   // (b) gl complete; Ab reads done

        if (ch < 63) {     // write ch+1 (issued one chunk ago: latency covered)
            #pragma unroll
            for (int p = 0; p < 4; ++p)
                *(uint4*)((char*)Ab + p * 8192 + tid * 16) = nvW[p];
            #pragma unroll
            for (int p = 0; p < 4; ++p) nvW[p] = nvF[p];
        }

        {
            int mloc = ch * 32 + erow;
            float x0 = xls[mloc * 2 + 0], x1 = xls[mloc * 2 + 1];
            int gbase = erow * 64 + ejp * 4;
            f32x4 qa = *(const f32x4*)&gl[0][0][gbase];
            qa += *(const f32x4*)&gl[1][0][gbase];
            f32x4 qb = *(const f32x4*)&gl[0][1][gbase];
            qb += *(const f32x4*)&gl[1][1][gbase];
            qa = deperm(qa, lgr); qb = deperm(qb, lgr);

            float cold0 = bf2f(cw & 0xffffu), cold1 = bf2f(cw >> 16);
            float i0 = sigm(qa[0] + b1v[0] + x0 * wiA[0] + x1 * wiB[0]);
            float f0 = sigm(qa[1] + b1v[2] + x0 * wiA[2] + x1 * wiB[2]);
            float g0 = tanh_(qa[2] + b1v[4] + x0 * wiA[4] + x1 * wiB[4]);
            float o0 = sigm(qa[3] + b1v[6] + x0 * wiA[6] + x1 * wiB[6]);
            float cn0 = f0 * cold0 + i0 * g0;
            float hn0 = o0 * tanh_(cn0);
            float i1 = sigm(qb[0] + b1v[1] + x0 * wiA[1] + x1 * wiB[1]);
            float f1 = sigm(qb[1] + b1v[3] + x0 * wiA[3] + x1 * wiB[3]);
            float g1 = tanh_(qb[2] + b1v[5] + x0 * wiA[5] + x1 * wiB[5]);
            float o1 = sigm(qb[3] + b1v[7] + x0 * wiA[7] + x1 * wiB[7]);
            float cn1 = f1 * cold1 + i1 * g1;
            float hn1 = o1 * tanh_(cn1);
            size_t cix = blkOff + (size_t)mloc * 32 + ejp * 2;
            *(unsigned*)(c1s + cix) = (unsigned)f2bf(cn0) | ((unsigned)f2bf(cn1) << 16);
            *(unsigned*)(h1W + cix) = (unsigned)f2bf(hn0) | ((unsigned)f2bf(hn1) << 16);
        }
    }
}

// ---------------- layer-2 (r4 structure + block-major + dist-2 prefetch) ----------------
__global__ __launch_bounds__(TPB, 2) void l2_kernel(
    const unsigned short* __restrict__ h1C, const unsigned short* __restrict__ h2R,
    unsigned short* __restrict__ h2W, unsigned short* __restrict__ c2s,
    float* __restrict__ pp,
    const unsigned short* __restrict__ PW2, const float* __restrict__ b2,
    const float* __restrict__ w_out)
{
    __shared__ __align__(16) unsigned short Ab[32768];     // 64 KB
    __shared__ __align__(16) float gl[2][2][2304];         // 36 KB

    const int tid = threadIdx.x, lane = tid & 63, w = tid >> 6;
    const int b = blockIdx.x;
    const int g = 2 * (b & 7) + (b >> 7);
    const int s = (b >> 3) & 15;
    const int l15 = lane & 15, lg = lane >> 4;
    const int cg = w & 1, kq = w >> 1;
    const int copy = kq >> 1, adder = ((kq & 1) == 0);
    const size_t gB = (size_t)g * 16;
    const size_t blkOff = (gB + s) * 2048 * 32;

    s16x8 bw[4][8];
    #pragma unroll
    for (int j = 0; j < 4; ++j)
        #pragma unroll
        for (int ksl = 0; ksl < 8; ++ksl)
            bw[j][ksl] = ((const s16x8*)PW2)[(((s * 8 + cg * 4 + j) * 32) + kq * 8 + ksl) * 64 + lane];

    const int erow = tid >> 4, ejp = tid & 15;
    const int lgr = w & 3;
    float b2v[8];
    #pragma unroll
    for (int q = 0; q < 8; ++q) {
        int dj = q & 1, gq = q >> 1;
        b2v[q] = b2[gq * 512 + s * 32 + ejp * 2 + dj];
    }
    float woA0 = w_out[s * 32 + ejp * 2], woA1 = w_out[s * 32 + ejp * 2 + 1];
    float woB0 = w_out[512 + s * 32 + ejp * 2], woB1 = w_out[512 + s * 32 + ejp * 2 + 1];

    const int st_ks4 = tid >> 7;     // ks = p*4 + st_ks4 (0..31)
    const int st_row = ((tid >> 6) & 1) * 16 + (tid & 15);
    const int st_lg  = (tid >> 4) & 3;

    uint4 nvW[8], nvF[8];
    #pragma unroll
    for (int p = 0; p < 8; ++p) {
        int ks = p * 4 + st_ks4;
        const unsigned short* base = (ks < 16) ? h1C : h2R;
        int ksl = (ks < 16) ? ks : (ks - 16);
        nvF[p] = *(const uint4*)(base + ((gB + ksl) * 2048 + st_row) * 32 + st_lg * 8);
    }
    #pragma unroll
    for (int p = 0; p < 8; ++p)
        *(uint4*)((char*)Ab + p * 8192 + tid * 16) = nvF[p];
    #pragma unroll
    for (int p = 0; p < 8; ++p) {
        int ks = p * 4 + st_ks4;
        const unsigned short* base = (ks < 16) ? h1C : h2R;
        int ksl = (ks < 16) ? ks : (ks - 16);
        nvW[p] = *(const uint4*)(base + ((gB + ksl) * 2048 + 32 + st_row) * 32 + st_lg * 8);
    }

    #pragma unroll 1
    for (int ch = 0; ch < 64; ++ch) {
        __syncthreads();   // (a) Ab ready

        if (ch < 62) {
            #pragma unroll
            for (int p = 0; p < 8; ++p) {
                int ks = p * 4 + st_ks4;
                const unsigned short* base = (ks < 16) ? h1C : h2R;
                int ksl = (ks < 16) ? ks : (ks - 16);
                nvF[p] = *(const uint4*)(base + ((gB + ksl) * 2048 + (ch + 2) * 32 + st_row) * 32 + st_lg * 8);
            }
        }
        unsigned cw = *(const unsigned*)(c2s + blkOff + (size_t)(ch * 32 + erow) * 32 + ejp * 2);

        f32x4 acc[2][4];
        #pragma unroll
        for (int rh = 0; rh < 2; ++rh)
            #pragma unroll
            for (int j = 0; j < 4; ++j) { acc[rh][j][0]=0.f; acc[rh][j][1]=0.f; acc[rh][j][2]=0.f; acc[rh][j][3]=0.f; }
        #pragma unroll
        for (int ksl = 0; ksl < 8; ++ksl) {
            int ks = kq * 8 + ksl;
            s16x8 a0 = *(const s16x8*)((const char*)Ab + ks * 2048 + lane * 16);
            s16x8 a1 = *(const s16x8*)((const char*)Ab + ks * 2048 + 1024 + lane * 16);
            #pragma unroll
            for (int j = 0; j < 4; ++j) {
                acc[0][j] = __builtin_amdgcn_mfma_f32_16x16x32_bf16(a0, bw[j][ksl], acc[0][j], 0, 0, 0);
                acc[1][j] = __builtin_amdgcn_mfma_f32_16x16x32_bf16(a1, bw[j][ksl], acc[1][j], 0, 0, 0);
            }
        }

        if (!adder) {
            #pragma unroll
            for (int j = 0; j < 4; ++j) {
                int col = (cg * 4 + j) * 16 + l15;
                int u = col & 31, gate = col >> 5;
                float* dst = &gl[copy][u & 1][(u >> 1) * 4 + (gate ^ lg)];
                #pragma unroll
                for (int rh = 0; rh < 2; ++rh)
                    #pragma unroll
                    for (int r = 0; r < 4; ++r)
                        dst[(rh * 16 + lg * 4 + r) * 64] = acc[rh][j][r];
            }
        }
        __syncthreads();   // (b) partial copies written
        if (adder) {
            #pragma unroll
            for (int j = 0; j < 4; ++j) {
                int col = (cg * 4 + j) * 16 + l15;
                int u = col & 31, gate = col >> 5;
                float* dst = &gl[copy][u & 1][(u >> 1) * 4 + (gate ^ lg)];
                #pragma unroll
                for (int rh = 0; rh < 2; ++rh)
                    #pragma unroll
                    for (int r = 0; r < 4; ++r)
                        dst[(rh * 16 + lg * 4 + r) * 64] += acc[rh][j][r];
            }
        }
        __syncthreads();   // (c) gl final; Ab reads done

        if (ch < 63) {
            #pragma unroll
            for (int p = 0; p < 8; ++p)
                *(uint4*)((char*)Ab + p * 8192 + tid * 16) = nvW[p];
            #pragma unroll
            for (int p = 0; p < 8; ++p) nvW[p] = nvF[p];
        }

        {
            int mloc = ch * 32 + erow;
            int gbase = erow * 64 + ejp * 4;
            f32x4 qa = *(const f32x4*)&gl[0][0][gbase];
            qa += *(const f32x4*)&gl[1][0][gbase];
            f32x4 qb = *(const f32x4*)&gl[0][1][gbase];
            qb += *(const f32x4*)&gl[1][1][gbase];
            qa = deperm(qa, lgr); qb = deperm(qb, lgr);

            float cold0 = bf2f(cw & 0xffffu), cold1 = bf2f(cw >> 16);
            float i0 = sigm(qa[0] + b2v[0]);
            float f0 = sigm(qa[1] + b2v[2]);
            float g0 = tanh_(qa[2] + b2v[4]);
            float o0 = sigm(qa[3] + b2v[6]);
            float cn0 = f0 * cold0 + i0 * g0;
            float hn0 = o0 * tanh_(cn0);
            float i1 = sigm(qb[0] + b2v[1]);
            float f1 = sigm(qb[1] + b2v[3]);
            float g1 = tanh_(qb[2] + b2v[5]);
            float o1 = sigm(qb[3] + b2v[7]);
            float cn1 = f1 * cold1 + i1 * g1;
            float hn1 = o1 * tanh_(cn1);
            size_t cix = blkOff + (size_t)mloc * 32 + ejp * 2;
            *(unsigned*)(c2s + cix) = (unsigned)f2bf(cn0) | ((unsigned)f2bf(cn1) << 16);
            *(unsigned*)(h2W + cix) = (unsigned)f2bf(hn0) | ((unsigned)f2bf(hn1) << 16);

            float p0 = hn0 * woA0 + hn1 * woA1;
            float p1 = hn0 * woB0 + hn1 * woB1;
            #pragma unroll
            for (int d = 1; d < 16; d <<= 1) {
                p0 += __shfl_xor(p0, d, 16);
                p1 += __shfl_xor(p1, d, 16);
            }
            if (ejp == 0)
                *(float2*)(pp + (((size_t)(g * 16 + s)) << 12) + (size_t)mloc * 2)
                    = make_float2(p0, p1);
        }
    }
}

// ---------------- final-step output ----------------
__global__ void tail_kernel(const float* __restrict__ pp, const float* __restrict__ b_out,
                            float* __restrict__ outp)
{
    int i = blockIdx.x * 256 + threadIdx.x;
    if (i < 65536) {
        int m = i >> 1, j = i & 1;
        int g = m >> 11;
        int idx = (m & 2047) * 2 + j;
        float sum = b_out[j];
        #pragma unroll 1
        for (int s = 0; s < 16; ++s)
            sum += pp[(((size_t)(g * 16 + s)) << 12) + idx];
        outp[(size_t)m * (2 * NSTEP) + (NSTEP - 1) * 2 + j] = sum;
    }
}

extern "C" void kernel_launch(void* const* d_in, const int* in_sizes, int n_in,
                              void* d_out, int out_size, void* d_ws, size_t ws_size,
                              hipStream_t stream)
{
    (void)in_sizes; (void)n_in; (void)out_size; (void)ws_size;
    const float* h        = (const float*)d_in[0];
    const float* w_init_h = (const float*)d_in[1];
    const float* b_init_h = (const float*)d_in[2];
    const float* w_init_c = (const float*)d_in[3];
    const float* b_init_c = (const float*)d_in[4];
    const float* w_ih0    = (const float*)d_in[5];
    const float* w_hh0    = (const float*)d_in[6];
    const float* b_ih0    = (const float*)d_in[7];
    const float* b_hh0    = (const float*)d_in[8];
    const float* w_ih1    = (const float*)d_in[9];
    const float* w_hh1    = (const float*)d_in[10];
    const float* b_ih1    = (const float*)d_in[11];
    const float* b_hh1    = (const float*)d_in[12];
    const float* w_out    = (const float*)d_in[13];
    const float* b_out    = (const float*)d_in[14];
    float* out = (float*)d_out;

    char* ws = (char*)d_ws;
    unsigned short* h1s[2] = { (unsigned short*)(ws + 0),
                               (unsigned short*)(ws + 33554432) };
    unsigned short* h2s[2] = { (unsigned short*)(ws + 67108864),
                               (unsigned short*)(ws + 100663296) };
    unsigned short* c1s = (unsigned short*)(ws + 134217728);
    unsigned short* c2s = (unsigned short*)(ws + 167772160);
    float* pp           = (float*)(ws + 201326592);   // 4 MB
    unsigned short* PW1 = (unsigned short*)(ws + 205520896);
    unsigned short* PW2 = (unsigned short*)(ws + 207618048);
    unsigned short* PI  = (unsigned short*)(ws + 211812352);
    float* b1 = (float*)(ws + 212860928);
    float* b2 = (float*)(ws + 212869120);

    pack_kernel<<<14352, 256, 0, stream>>>(w_hh0, w_ih1, w_hh1, w_init_h, w_init_c,
                                           b_ih0, b_hh0, b_ih1, b_hh1, PW1, PW2, PI, b1, b2);
    init_kernel<<<32768 / BMI, TPB, 0, stream>>>(h, PI, b_init_h, b_init_c,
                                                 h1s[1], h2s[1], c1s, c2s);
    for (int t = 0; t < NSTEP; ++t) {
        const unsigned short* h1R = h1s[(t + 1) & 1];
        unsigned short* h1W = h1s[t & 1];
        const unsigned short* h2R = h2s[(t + 1) & 1];
        unsigned short* h2W = h2s[t & 1];
        l1_kernel<<<256, 512, 0, stream>>>(h1R, h1W, c1s, pp, out, PW1, b1, w_ih0, b_out, t);
        l2_kernel<<<256, 512, 0, stream>>>(h1W, h2R, h2W, c2s, pp, PW2, b2, w_out);
    }
    tail_kernel<<<256, 256, 0, stream>>>(pp, b_out, out);
}

// Round 8
// 41114.154 us; speedup vs baseline: 3.5685x; 1.4341x over previous
//
#include <hip/hip_runtime.h>

#define HID    512
#define TPB    512
#define NSTEP  60
#define BMI    64

using f32x4 = __attribute__((ext_vector_type(4))) float;
using s16x8 = __attribute__((ext_vector_type(8))) short;

__device__ __forceinline__ unsigned short f2bf(float f) {
    unsigned u = __builtin_bit_cast(unsigned, f);
    u += 0x7fffu + ((u >> 16) & 1u);
    return (unsigned short)(u >> 16);
}
__device__ __forceinline__ float bf2f(unsigned u) {
    return __builtin_bit_cast(float, u << 16);
}
__device__ __forceinline__ float sigm(float x) { return 1.0f / (1.0f + __expf(-x)); }
__device__ __forceinline__ float tanh_(float x) { return 1.0f - 2.0f / (__expf(2.0f * x) + 1.0f); }

__device__ __forceinline__ f32x4 deperm(f32x4 q, int lgr) {
    f32x4 p;
    if (lgr == 0)      { p[0]=q[0]; p[1]=q[1]; p[2]=q[2]; p[3]=q[3]; }
    else if (lgr == 1) { p[0]=q[1]; p[1]=q[0]; p[2]=q[3]; p[3]=q[2]; }
    else if (lgr == 2) { p[0]=q[2]; p[1]=q[3]; p[2]=q[0]; p[3]=q[1]; }
    else               { p[0]=q[3]; p[1]=q[2]; p[2]=q[1]; p[3]=q[0]; }
    return p;
}

// ---------------- weight packing (identical to r3/r4 — verified) ----------------
__global__ void pack_kernel(const float* __restrict__ w_hh0, const float* __restrict__ w_ih1,
                            const float* __restrict__ w_hh1, const float* __restrict__ w_init_h,
                            const float* __restrict__ w_init_c,
                            const float* __restrict__ b_ih0, const float* __restrict__ b_hh0,
                            const float* __restrict__ b_ih1, const float* __restrict__ b_hh1,
                            unsigned short* __restrict__ PW1, unsigned short* __restrict__ PW2,
                            unsigned short* __restrict__ PI,
                            float* __restrict__ b1, float* __restrict__ b2)
{
    int idx = blockIdx.x * 256 + threadIdx.x;
    if (idx < 1048576) {
        int el = idx & 511, fr = idx >> 9;
        int ks = fr & 15, ct = (fr >> 4) & 7, s = fr >> 7;
        int lane = el >> 3, e = el & 7;
        int cl = ct * 16 + (lane & 15);
        int gcol = (cl >> 5) * 512 + s * 32 + (cl & 31);
        int k = ks * 32 + (lane >> 4) * 8 + e;
        PW1[idx] = f2bf(w_hh0[gcol * 512 + k]);
        return;
    }
    int i2 = idx - 1048576;
    if (i2 >= 0 && i2 < 2097152) {
        int el = i2 & 511, fr = i2 >> 9;
        int ks = fr & 31, ct = (fr >> 5) & 7, s = fr >> 8;
        int lane = el >> 3, e = el & 7;
        int cl = ct * 16 + (lane & 15);
        int gcol = (cl >> 5) * 512 + s * 32 + (cl & 31);
        int kk = (ks & 15) * 32 + (lane >> 4) * 8 + e;
        float v = (ks < 16) ? w_ih1[gcol * 512 + kk] : w_hh1[gcol * 512 + kk];
        PW2[i2] = f2bf(v);
        return;
    }
    int i3 = idx - (1048576 + 2097152);
    if (i3 >= 0 && i3 < 524288) {
        int el = i3 & 511, fr = i3 >> 9;
        int ks = fr & 15, tile = fr >> 4;
        int s = tile >> 5, c = tile & 31;
        int lane = el >> 3, e = el & 7;
        int n = c * 16 + (lane & 15);
        int k = ks * 32 + (lane >> 4) * 8 + e;
        float v = s ? w_init_c[n * 512 + k] : w_init_h[n * 512 + k];
        PI[i3] = f2bf(v);
        return;
    }
    int i4 = idx - (1048576 + 2097152 + 524288);
    if (i4 >= 0 && i4 < 2048) b1[i4] = b_ih0[i4] + b_hh0[i4];
    else if (i4 >= 2048 && i4 < 4096) b2[i4 - 2048] = b_ih1[i4 - 2048] + b_hh1[i4 - 2048];
}

// ---------------- init (r4 version, interleaved [m][512] state) ----------------
__global__ __launch_bounds__(TPB, 2) void init_kernel(
    const float* __restrict__ hin, const unsigned short* __restrict__ PI,
    const float* __restrict__ b_init_h, const float* __restrict__ b_init_c,
    unsigned short* __restrict__ h1s, unsigned short* __restrict__ h2s,
    unsigned short* __restrict__ c1s, unsigned short* __restrict__ c2s)
{
    __shared__ unsigned short bufA[BMI * HID];
    const int tid = threadIdx.x, lane = tid & 63, wave = tid >> 6;
    const int m0 = blockIdx.x * BMI;
    const int l15 = lane & 15, lg = lane >> 4;
    const int swz = (lane & 7) << 4;

    for (int j = 0; j < 16; ++j) {
        int e = tid * 4 + j * 2048;
        int row = e >> 9, col = e & 511;
        float4 v = *(const float4*)(hin + (size_t)(m0 + row) * HID + col);
        ushort4 w;
        w.x = f2bf(v.x); w.y = f2bf(v.y); w.z = f2bf(v.z); w.w = f2bf(v.w);
        int L = (row * 1024 + col * 2) ^ ((row & 7) << 4);
        *(ushort4*)((char*)bufA + L) = w;
    }
    __syncthreads();

    #pragma unroll 1
    for (int cc = 0; cc < 4; ++cc) {
        int c = wave * 4 + cc;
        int nc = c * 16 + l15;
        f32x4 acc[4][2];
        #pragma unroll
        for (int rt = 0; rt < 4; ++rt)
            #pragma unroll
            for (int s = 0; s < 2; ++s)
                #pragma unroll
                for (int r = 0; r < 4; ++r) acc[rt][s][r] = 0.0f;

        #pragma unroll
        for (int ks = 0; ks < 16; ++ks) {
            s16x8 a[4];
            #pragma unroll
            for (int rt = 0; rt < 4; ++rt) {
                int ao = (rt * 16 + l15) * 1024 + ((ks * 64 + lg * 16) ^ swz);
                a[rt] = *(const s16x8*)((const char*)bufA + ao);
            }
            #pragma unroll
            for (int s = 0; s < 2; ++s) {
                s16x8 b = ((const s16x8*)PI)[((s * 32 + c) * 16 + ks) * 64 + lane];
                #pragma unroll
                for (int rt = 0; rt < 4; ++rt)
                    acc[rt][s] = __builtin_amdgcn_mfma_f32_16x16x32_bf16(a[rt], b, acc[rt][s], 0, 0, 0);
            }
        }
        float bh = b_init_h[nc], bc = b_init_c[nc];
        #pragma unroll
        for (int rt = 0; rt < 4; ++rt)
            #pragma unroll
            for (int r = 0; r < 4; ++r) {
                int m = m0 + rt * 16 + lg * 4 + r;
                float hv = acc[rt][0][r] + bh;
                float cv = acc[rt][1][r] + bc;
                unsigned short hb = f2bf(hv);
                size_t o = (size_t)m * HID + nc;
                h1s[o] = hb; h2s[o] = hb;
                c1s[o] = f2bf(cv); c2s[o] = f2bf(cv);
            }
    }
}

// ---------------- layer-1 (r4 structure; nt state stores) ----------------
__global__ __launch_bounds__(TPB, 2) void l1_kernel(
    const unsigned short* __restrict__ h1R, unsigned short* __restrict__ h1W,
    unsigned short* __restrict__ c1s, const float* __restrict__ pp,
    float* __restrict__ outp, const unsigned short* __restrict__ PW1,
    const float* __restrict__ b1, const float* __restrict__ w_ih0,
    const float* __restrict__ b_out, int t)
{
    __shared__ __align__(16) unsigned short Ab[16384];     // 32 KB
    __shared__ __align__(16) float gl[2][2][2048];         // 32 KB
    __shared__ __align__(16) float xls[5120];              // 20 KB (4096 used)

    const int tid = threadIdx.x, lane = tid & 63, w = tid >> 6;
    const int b = blockIdx.x;
    const int g = 2 * (b & 7) + (b >> 7);
    const int s = (b >> 3) & 15;
    const int m0 = g * 2048;
    const int l15 = lane & 15, lg = lane >> 4;
    const int cg = w & 1, kh = (w >> 1) & 1, rha = w >> 2;

    s16x8 bw[4][8];
    #pragma unroll
    for (int j = 0; j < 4; ++j)
        #pragma unroll
        for (int ksl = 0; ksl < 8; ++ksl)
            bw[j][ksl] = ((const s16x8*)PW1)[(((s * 8 + cg * 4 + j) * 16) + kh * 8 + ksl) * 64 + lane];

    const int erow = tid >> 4, ejp = tid & 15;
    const int lgr = w & 3;
    float b1v[8], wiA[8], wiB[8];
    #pragma unroll
    for (int q = 0; q < 8; ++q) {
        int dj = q & 1, gq = q >> 1;
        int gcol = gq * 512 + s * 32 + ejp * 2 + dj;
        b1v[q] = b1[gcol];
        wiA[q] = w_ih0[gcol * 2 + 0];
        wiB[q] = w_ih0[gcol * 2 + 1];
    }
    float bo0 = b_out[0], bo1 = b_out[1];

    // ---- reduce prev-step partials -> xls; write out[:,t-1] ----
    if (t == 0) {
        #pragma unroll
        for (int i = 0; i < 8; ++i) xls[tid * 8 + i] = 0.0f;
    } else {
        f32x4 s0 = {0.f,0.f,0.f,0.f}, s1 = {0.f,0.f,0.f,0.f};
        #pragma unroll 1
        for (int ss = 0; ss < 16; ++ss) {
            const float* p = pp + (((size_t)(g * 16 + ss)) << 12) + tid * 8;
            s0 += *(const f32x4*)p;
            s1 += *(const f32x4*)(p + 4);
        }
        s0[0] += bo0; s0[1] += bo1; s0[2] += bo0; s0[3] += bo1;
        s1[0] += bo0; s1[1] += bo1; s1[2] += bo0; s1[3] += bo1;
        *(f32x4*)(xls + tid * 8) = s0;
        *(f32x4*)(xls + tid * 8 + 4) = s1;
        if (s == 0) {
            float* ob = outp + (size_t)(m0 + tid * 4) * (2 * NSTEP) + (t - 1) * 2;
            *(float2*)(ob)                 = make_float2(s0[0], s0[1]);
            *(float2*)(ob + 2 * NSTEP)     = make_float2(s0[2], s0[3]);
            *(float2*)(ob + 4 * NSTEP)     = make_float2(s1[0], s1[1]);
            *(float2*)(ob + 6 * NSTEP)     = make_float2(s1[2], s1[3]);
        }
    }

    const int st_l15 = tid & 15, st_lg = (tid >> 4) & 3, st_rh = (tid >> 6) & 1, st_kq = tid >> 7;
    const int st_grow = st_rh * 16 + st_l15;

    uint4 nv[4];
    #pragma unroll
    for (int p = 0; p < 4; ++p) {
        int ks = p * 4 + st_kq;
        nv[p] = *(const uint4*)(h1R + (size_t)(m0 + st_grow) * HID + ks * 32 + st_lg * 8);
    }
    #pragma unroll
    for (int p = 0; p < 4; ++p)
        *(uint4*)((char*)Ab + p * 8192 + tid * 16) = nv[p];

    #pragma unroll 1
    for (int ch = 0; ch < 64; ++ch) {
        __syncthreads();   // (a) Ab + xls ready; prev epilogue done with gl

        if (ch < 63) {
            #pragma unroll
            for (int p = 0; p < 4; ++p) {
                int ks = p * 4 + st_kq;
                nv[p] = *(const uint4*)(h1R + (size_t)(m0 + (ch + 1) * 32 + st_grow) * HID + ks * 32 + st_lg * 8);
            }
        }

        f32x4 acc[4];
        #pragma unroll
        for (int j = 0; j < 4; ++j) { acc[j][0]=0.f; acc[j][1]=0.f; acc[j][2]=0.f; acc[j][3]=0.f; }
        #pragma unroll
        for (int ksl = 0; ksl < 8; ++ksl) {
            int ks = kh * 8 + ksl;
            s16x8 a = *(const s16x8*)((const char*)Ab + ks * 2048 + rha * 1024 + lane * 16);
            #pragma unroll
            for (int j = 0; j < 4; ++j)
                acc[j] = __builtin_amdgcn_mfma_f32_16x16x32_bf16(a, bw[j][ksl], acc[j], 0, 0, 0);
        }
        #pragma unroll
        for (int j = 0; j < 4; ++j) {
            int col = (cg * 4 + j) * 16 + l15;
            int u = col & 31, gate = col >> 5;
            float* dst = &gl[kh][u & 1][(u >> 1) * 4 + (gate ^ lg)];
            #pragma unroll
            for (int r = 0; r < 4; ++r)
                dst[(rha * 16 + lg * 4 + r) * 64] = acc[j][r];
        }
        __syncthreads();   // (b) gl complete; Ab reads done

        if (ch < 63) {
            #pragma unroll
            for (int p = 0; p < 4; ++p)
                *(uint4*)((char*)Ab + p * 8192 + tid * 16) = nv[p];
        }

        {
            int grow = ch * 32 + erow;
            int m = m0 + grow;
            float x0 = xls[grow * 2 + 0], x1 = xls[grow * 2 + 1];
            int gbase = erow * 64 + ejp * 4;
            f32x4 qa = *(const f32x4*)&gl[0][0][gbase];
            qa += *(const f32x4*)&gl[1][0][gbase];
            f32x4 qb = *(const f32x4*)&gl[0][1][gbase];
            qb += *(const f32x4*)&gl[1][1][gbase];
            qa = deperm(qa, lgr); qb = deperm(qb, lgr);

            int cix = m * HID + s * 32 + ejp * 2;
            unsigned cp = *(const unsigned*)(c1s + cix);
            float cold0 = bf2f(cp & 0xffffu), cold1 = bf2f(cp >> 16);
            float i0 = sigm(qa[0] + b1v[0] + x0 * wiA[0] + x1 * wiB[0]);
            float f0 = sigm(qa[1] + b1v[2] + x0 * wiA[2] + x1 * wiB[2]);
            float g0 = tanh_(qa[2] + b1v[4] + x0 * wiA[4] + x1 * wiB[4]);
            float o0 = sigm(qa[3] + b1v[6] + x0 * wiA[6] + x1 * wiB[6]);
            float cn0 = f0 * cold0 + i0 * g0;
            float hn0 = o0 * tanh_(cn0);
            float i1 = sigm(qb[0] + b1v[1] + x0 * wiA[1] + x1 * wiB[1]);
            float f1 = sigm(qb[1] + b1v[3] + x0 * wiA[3] + x1 * wiB[3]);
            float g1 = tanh_(qb[2] + b1v[5] + x0 * wiA[5] + x1 * wiB[5]);
            float o1 = sigm(qb[3] + b1v[7] + x0 * wiA[7] + x1 * wiB[7]);
            float cn1 = f1 * cold1 + i1 * g1;
            float hn1 = o1 * tanh_(cn1);
            __builtin_nontemporal_store((unsigned)f2bf(cn0) | ((unsigned)f2bf(cn1) << 16),
                                        (unsigned*)(c1s + cix));
            __builtin_nontemporal_store((unsigned)f2bf(hn0) | ((unsigned)f2bf(hn1) << 16),
                                        (unsigned*)(h1W + cix));
        }
    }
}

// ---------------- layer-2 (r4 structure; nt state stores) ----------------
__global__ __launch_bounds__(TPB, 2) void l2_kernel(
    const unsigned short* __restrict__ h1C, const unsigned short* __restrict__ h2R,
    unsigned short* __restrict__ h2W, unsigned short* __restrict__ c2s,
    float* __restrict__ pp,
    const unsigned short* __restrict__ PW2, const float* __restrict__ b2,
    const float* __restrict__ w_out)
{
    __shared__ __align__(16) unsigned short Ab[32768];     // 64 KB
    __shared__ __align__(16) float gl[2][2][2304];         // 36 KB

    const int tid = threadIdx.x, lane = tid & 63, w = tid >> 6;
    const int b = blockIdx.x;
    const int g = 2 * (b & 7) + (b >> 7);
    const int s = (b >> 3) & 15;
    const int m0 = g * 2048;
    const int l15 = lane & 15, lg = lane >> 4;
    const int cg = w & 1, kq = w >> 1;
    const int copy = kq >> 1, adder = ((kq & 1) == 0);

    s16x8 bw[4][8];
    #pragma unroll
    for (int j = 0; j < 4; ++j)
        #pragma unroll
        for (int ksl = 0; ksl < 8; ++ksl)
            bw[j][ksl] = ((const s16x8*)PW2)[(((s * 8 + cg * 4 + j) * 32) + kq * 8 + ksl) * 64 + lane];

    const int erow = tid >> 4, ejp = tid & 15;
    const int lgr = w & 3;
    float b2v[8];
    #pragma unroll
    for (int q = 0; q < 8; ++q) {
        int dj = q & 1, gq = q >> 1;
        b2v[q] = b2[gq * 512 + s * 32 + ejp * 2 + dj];
    }
    float woA0 = w_out[s * 32 + ejp * 2], woA1 = w_out[s * 32 + ejp * 2 + 1];
    float woB0 = w_out[512 + s * 32 + ejp * 2], woB1 = w_out[512 + s * 32 + ejp * 2 + 1];

    const int st_l15 = tid & 15, st_lg = (tid >> 4) & 3, st_rh = (tid >> 6) & 1, st_kq = tid >> 7;
    const int st_grow = st_rh * 16 + st_l15;

    uint4 nv[8];
    #pragma unroll
    for (int p = 0; p < 8; ++p) {
        int ks = p * 4 + st_kq;
        const unsigned short* src = (ks < 16) ? h1C : h2R;
        int kel = (ks < 16) ? ks : (ks - 16);
        nv[p] = *(const uint4*)(src + (size_t)(m0 + st_grow) * HID + kel * 32 + st_lg * 8);
    }
    #pragma unroll
    for (int p = 0; p < 8; ++p)
        *(uint4*)((char*)Ab + p * 8192 + tid * 16) = nv[p];

    #pragma unroll 1
    for (int ch = 0; ch < 64; ++ch) {
        __syncthreads();   // (a) Ab ready

        if (ch < 63) {
            #pragma unroll
            for (int p = 0; p < 8; ++p) {
                int ks = p * 4 + st_kq;
                const unsigned short* src = (ks < 16) ? h1C : h2R;
                int kel = (ks < 16) ? ks : (ks - 16);
                nv[p] = *(const uint4*)(src + (size_t)(m0 + (ch + 1) * 32 + st_grow) * HID + kel * 32 + st_lg * 8);
            }
        }

        f32x4 acc[2][4];
        #pragma unroll
        for (int rh = 0; rh < 2; ++rh)
            #pragma unroll
            for (int j = 0; j < 4; ++j) { acc[rh][j][0]=0.f; acc[rh][j][1]=0.f; acc[rh][j][2]=0.f; acc[rh][j][3]=0.f; }
        #pragma unroll
        for (int ksl = 0; ksl < 8; ++ksl) {
            int ks = kq * 8 + ksl;
            s16x8 a0 = *(const s16x8*)((const char*)Ab + ks * 2048 + lane * 16);
            s16x8 a1 = *(const s16x8*)((const char*)Ab + ks * 2048 + 1024 + lane * 16);
            #pragma unroll
            for (int j = 0; j < 4; ++j) {
                acc[0][j] = __builtin_amdgcn_mfma_f32_16x16x32_bf16(a0, bw[j][ksl], acc[0][j], 0, 0, 0);
                acc[1][j] = __builtin_amdgcn_mfma_f32_16x16x32_bf16(a1, bw[j][ksl], acc[1][j], 0, 0, 0);
            }
        }

        if (!adder) {
            #pragma unroll
            for (int j = 0; j < 4; ++j) {
                int col = (cg * 4 + j) * 16 + l15;
                int u = col & 31, gate = col >> 5;
                float* dst = &gl[copy][u & 1][(u >> 1) * 4 + (gate ^ lg)];
                #pragma unroll
                for (int rh = 0; rh < 2; ++rh)
                    #pragma unroll
                    for (int r = 0; r < 4; ++r)
                        dst[(rh * 16 + lg * 4 + r) * 64] = acc[rh][j][r];
            }
        }
        __syncthreads();   // (b) partial copies written
        if (adder) {
            #pragma unroll
            for (int j = 0; j < 4; ++j) {
                int col = (cg * 4 + j) * 16 + l15;
                int u = col & 31, gate = col >> 5;
                float* dst = &gl[copy][u & 1][(u >> 1) * 4 + (gate ^ lg)];
                #pragma unroll
                for (int rh = 0; rh < 2; ++rh)
                    #pragma unroll
                    for (int r = 0; r < 4; ++r)
                        dst[(rh * 16 + lg * 4 + r) * 64] += acc[rh][j][r];
            }
        }
        __syncthreads();   // (c) gl final

        if (ch < 63) {
            #pragma unroll
            for (int p = 0; p < 8; ++p)
                *(uint4*)((char*)Ab + p * 8192 + tid * 16) = nv[p];
        }

        {
            int m = m0 + ch * 32 + erow;
            int gbase = erow * 64 + ejp * 4;
            f32x4 qa = *(const f32x4*)&gl[0][0][gbase];
            qa += *(const f32x4*)&gl[1][0][gbase];
            f32x4 qb = *(const f32x4*)&gl[0][1][gbase];
            qb += *(const f32x4*)&gl[1][1][gbase];
            qa = deperm(qa, lgr); qb = deperm(qb, lgr);

            int cix = m * HID + s * 32 + ejp * 2;
            unsigned cp = *(const unsigned*)(c2s + cix);
            float cold0 = bf2f(cp & 0xffffu), cold1 = bf2f(cp >> 16);
            float i0 = sigm(qa[0] + b2v[0]);
            float f0 = sigm(qa[1] + b2v[2]);
            float g0 = tanh_(qa[2] + b2v[4]);
            float o0 = sigm(qa[3] + b2v[6]);
            float cn0 = f0 * cold0 + i0 * g0;
            float hn0 = o0 * tanh_(cn0);
            float i1 = sigm(qb[0] + b2v[1]);
            float f1 = sigm(qb[1] + b2v[3]);
            float g1 = tanh_(qb[2] + b2v[5]);
            float o1 = sigm(qb[3] + b2v[7]);
            float cn1 = f1 * cold1 + i1 * g1;
            float hn1 = o1 * tanh_(cn1);
            __builtin_nontemporal_store((unsigned)f2bf(cn0) | ((unsigned)f2bf(cn1) << 16),
                                        (unsigned*)(c2s + cix));
            __builtin_nontemporal_store((unsigned)f2bf(hn0) | ((unsigned)f2bf(hn1) << 16),
                                        (unsigned*)(h2W + cix));

            float p0 = hn0 * woA0 + hn1 * woA1;
            float p1 = hn0 * woB0 + hn1 * woB1;
            #pragma unroll
            for (int d = 1; d < 16; d <<= 1) {
                p0 += __shfl_xor(p0, d, 16);
                p1 += __shfl_xor(p1, d, 16);
            }
            if (ejp == 0)
                *(float2*)(pp + (((size_t)(g * 16 + s)) << 12) + (size_t)(ch * 32 + erow) * 2)
                    = make_float2(p0, p1);
        }
    }
}

// ---------------- final-step output ----------------
__global__ void tail_kernel(const float* __restrict__ pp, const float* __restrict__ b_out,
                            float* __restrict__ outp)
{
    int i = blockIdx.x * 256 + threadIdx.x;
    if (i < 65536) {
        int m = i >> 1, j = i & 1;
        int g = m >> 11;
        int idx = (m & 2047) * 2 + j;
        float sum = b_out[j];
        #pragma unroll 1
        for (int s = 0; s < 16; ++s)
            sum += pp[(((size_t)(g * 16 + s)) << 12) + idx];
        outp[(size_t)m * (2 * NSTEP) + (NSTEP - 1) * 2 + j] = sum;
    }
}

extern "C" void kernel_launch(void* const* d_in, const int* in_sizes, int n_in,
                              void* d_out, int out_size, void* d_ws, size_t ws_size,
                              hipStream_t stream)
{
    (void)in_sizes; (void)n_in; (void)out_size; (void)ws_size;
    const float* h        = (const float*)d_in[0];
    const float* w_init_h = (const float*)d_in[1];
    const float* b_init_h = (const float*)d_in[2];
    const float* w_init_c = (const float*)d_in[3];
    const float* b_init_c = (const float*)d_in[4];
    const float* w_ih0    = (const float*)d_in[5];
    const float* w_hh0    = (const float*)d_in[6];
    const float* b_ih0    = (const float*)d_in[7];
    const float* b_hh0    = (const float*)d_in[8];
    const float* w_ih1    = (const float*)d_in[9];
    const float* w_hh1    = (const float*)d_in[10];
    const float* b_ih1    = (const float*)d_in[11];
    const float* b_hh1    = (const float*)d_in[12];
    const float* w_out    = (const float*)d_in[13];
    const float* b_out    = (const float*)d_in[14];
    float* out = (float*)d_out;

    char* ws = (char*)d_ws;
    unsigned short* h1s[2] = { (unsigned short*)(ws + 0),
                               (unsigned short*)(ws + 33554432) };
    unsigned short* h2s[2] = { (unsigned short*)(ws + 67108864),
                               (unsigned short*)(ws + 100663296) };
    unsigned short* c1s = (unsigned short*)(ws + 134217728);
    unsigned short* c2s = (unsigned short*)(ws + 167772160);
    float* pp           = (float*)(ws + 201326592);   // 4 MB
    unsigned short* PW1 = (unsigned short*)(ws + 205520896);
    unsigned short* PW2 = (unsigned short*)(ws + 207618048);
    unsigned short* PI  = (unsigned short*)(ws + 211812352);
    float* b1 = (float*)(ws + 212860928);
    float* b2 = (float*)(ws + 212869120);

    pack_kernel<<<14352, 256, 0, stream>>>(w_hh0, w_ih1, w_hh1, w_init_h, w_init_c,
                                           b_ih0, b_hh0, b_ih1, b_hh1, PW1, PW2, PI, b1, b2);
    init_kernel<<<32768 / BMI, TPB, 0, stream>>>(h, PI, b_init_h, b_init_c,
                                                 h1s[1], h2s[1], c1s, c2s);
    for (int t = 0; t < NSTEP; ++t) {
        const unsigned short* h1R = h1s[(t + 1) & 1];
        unsigned short* h1W = h1s[t & 1];
        const unsigned short* h2R = h2s[(t + 1) & 1];
        unsigned short* h2W = h2s[t & 1];
        l1_kernel<<<256, TPB, 0, stream>>>(h1R, h1W, c1s, pp, out, PW1, b1, w_ih0, b_out, t);
        l2_kernel<<<256, TPB, 0, stream>>>(h1W, h2R, h2W, c2s, pp, PW2, b2, w_out);
    }
    tail_kernel<<<256, 256, 0, stream>>>(pp, b_out, out);
}

// Round 10
// 38212.704 us; speedup vs baseline: 3.8395x; 1.0759x over previous
//
#include <hip/hip_runtime.h>

#define HID    512
#define TPB    512
#define NSTEP  60
#define BMI    64

using f32x4 = __attribute__((ext_vector_type(4))) float;
using s16x8 = __attribute__((ext_vector_type(8))) short;

__device__ __forceinline__ unsigned short f2bf(float f) {
    unsigned u = __builtin_bit_cast(unsigned, f);
    u += 0x7fffu + ((u >> 16) & 1u);
    return (unsigned short)(u >> 16);
}
__device__ __forceinline__ float bf2f(unsigned u) {
    return __builtin_bit_cast(float, u << 16);
}
__device__ __forceinline__ float sigm(float x) { return 1.0f / (1.0f + __expf(-x)); }
__device__ __forceinline__ float tanh_(float x) { return 1.0f - 2.0f / (__expf(2.0f * x) + 1.0f); }

// ---------------- weight packing ----------------
// Col mapping inside each 16-col MFMA tile: col c -> gate (c&3), unit ct*4+(c>>2).
// PW1: [s16][ct8][ks16][lane64][e8] from w_hh0.  PW2: [s16][ct8][ks32][lane][e]; ks<16 w_ih1, ks>=16 w_hh1.
// PI unchanged (init kernel).  b1 = b_ih0+b_hh0 ; b2 = b_ih1+b_hh1
__global__ void pack_kernel(const float* __restrict__ w_hh0, const float* __restrict__ w_ih1,
                            const float* __restrict__ w_hh1, const float* __restrict__ w_init_h,
                            const float* __restrict__ w_init_c,
                            const float* __restrict__ b_ih0, const float* __restrict__ b_hh0,
                            const float* __restrict__ b_ih1, const float* __restrict__ b_hh1,
                            unsigned short* __restrict__ PW1, unsigned short* __restrict__ PW2,
                            unsigned short* __restrict__ PI,
                            float* __restrict__ b1, float* __restrict__ b2)
{
    int idx = blockIdx.x * 256 + threadIdx.x;
    if (idx < 1048576) {
        int el = idx & 511, fr = idx >> 9;
        int ks = fr & 15, ct = (fr >> 4) & 7, s = fr >> 7;
        int lane = el >> 3, e = el & 7;
        int l15 = lane & 15;
        int gcol = (l15 & 3) * 512 + s * 32 + ct * 4 + (l15 >> 2);
        int k = ks * 32 + (lane >> 4) * 8 + e;
        PW1[idx] = f2bf(w_hh0[gcol * 512 + k]);
        return;
    }
    int i2 = idx - 1048576;
    if (i2 >= 0 && i2 < 2097152) {
        int el = i2 & 511, fr = i2 >> 9;
        int ks = fr & 31, ct = (fr >> 5) & 7, s = fr >> 8;
        int lane = el >> 3, e = el & 7;
        int l15 = lane & 15;
        int gcol = (l15 & 3) * 512 + s * 32 + ct * 4 + (l15 >> 2);
        int kk = (ks & 15) * 32 + (lane >> 4) * 8 + e;
        float v = (ks < 16) ? w_ih1[gcol * 512 + kk] : w_hh1[gcol * 512 + kk];
        PW2[i2] = f2bf(v);
        return;
    }
    int i3 = idx - (1048576 + 2097152);
    if (i3 >= 0 && i3 < 524288) {
        int el = i3 & 511, fr = i3 >> 9;
        int ks = fr & 15, tile = fr >> 4;
        int s = tile >> 5, c = tile & 31;
        int lane = el >> 3, e = el & 7;
        int n = c * 16 + (lane & 15);
        int k = ks * 32 + (lane >> 4) * 8 + e;
        float v = s ? w_init_c[n * 512 + k] : w_init_h[n * 512 + k];
        PI[i3] = f2bf(v);
        return;
    }
    int i4 = idx - (1048576 + 2097152 + 524288);
    if (i4 >= 0 && i4 < 2048) b1[i4] = b_ih0[i4] + b_hh0[i4];
    else if (i4 >= 2048 && i4 < 4096) b2[i4 - 2048] = b_ih1[i4 - 2048] + b_hh1[i4 - 2048];
}

// ---------------- init (r4 version, interleaved [m][512] state) ----------------
__global__ __launch_bounds__(TPB, 2) void init_kernel(
    const float* __restrict__ hin, const unsigned short* __restrict__ PI,
    const float* __restrict__ b_init_h, const float* __restrict__ b_init_c,
    unsigned short* __restrict__ h1s, unsigned short* __restrict__ h2s,
    unsigned short* __restrict__ c1s, unsigned short* __restrict__ c2s)
{
    __shared__ unsigned short bufA[BMI * HID];
    const int tid = threadIdx.x, lane = tid & 63, wave = tid >> 6;
    const int m0 = blockIdx.x * BMI;
    const int l15 = lane & 15, lg = lane >> 4;
    const int swz = (lane & 7) << 4;

    for (int j = 0; j < 16; ++j) {
        int e = tid * 4 + j * 2048;
        int row = e >> 9, col = e & 511;
        float4 v = *(const float4*)(hin + (size_t)(m0 + row) * HID + col);
        ushort4 w;
        w.x = f2bf(v.x); w.y = f2bf(v.y); w.z = f2bf(v.z); w.w = f2bf(v.w);
        int L = (row * 1024 + col * 2) ^ ((row & 7) << 4);
        *(ushort4*)((char*)bufA + L) = w;
    }
    __syncthreads();

    #pragma unroll 1
    for (int cc = 0; cc < 4; ++cc) {
        int c = wave * 4 + cc;
        int nc = c * 16 + l15;
        f32x4 acc[4][2];
        #pragma unroll
        for (int rt = 0; rt < 4; ++rt)
            #pragma unroll
            for (int s = 0; s < 2; ++s)
                #pragma unroll
                for (int r = 0; r < 4; ++r) acc[rt][s][r] = 0.0f;

        #pragma unroll
        for (int ks = 0; ks < 16; ++ks) {
            s16x8 a[4];
            #pragma unroll
            for (int rt = 0; rt < 4; ++rt) {
                int ao = (rt * 16 + l15) * 1024 + ((ks * 64 + lg * 16) ^ swz);
                a[rt] = *(const s16x8*)((const char*)bufA + ao);
            }
            #pragma unroll
            for (int s = 0; s < 2; ++s) {
                s16x8 b = ((const s16x8*)PI)[((s * 32 + c) * 16 + ks) * 64 + lane];
                #pragma unroll
                for (int rt = 0; rt < 4; ++rt)
                    acc[rt][s] = __builtin_amdgcn_mfma_f32_16x16x32_bf16(a[rt], b, acc[rt][s], 0, 0, 0);
            }
        }
        float bh = b_init_h[nc], bc = b_init_c[nc];
        #pragma unroll
        for (int rt = 0; rt < 4; ++rt)
            #pragma unroll
            for (int r = 0; r < 4; ++r) {
                int m = m0 + rt * 16 + lg * 4 + r;
                float hv = acc[rt][0][r] + bh;
                float cv = acc[rt][1][r] + bc;
                unsigned short hb = f2bf(hv);
                size_t o = (size_t)m * HID + nc;
                h1s[o] = hb; h2s[o] = hb;
                c1s[o] = f2bf(cv); c2s[o] = f2bf(cv);
            }
    }
}

// ---------------- layer-1: per-wave full-K, LDS-scratch transpose epilogue, 1 barrier/chunk ----------------
__global__ __launch_bounds__(TPB, 2) void l1_kernel(
    const unsigned short* __restrict__ h1R, unsigned short* __restrict__ h1W,
    unsigned short* __restrict__ c1s, const float* __restrict__ pp,
    float* __restrict__ outp, const unsigned short* __restrict__ PW1,
    const float* __restrict__ b1, const float* __restrict__ w_ih0,
    const float* __restrict__ b_out, int t)
{
    __shared__ __align__(16) unsigned short Ab[2 * 16384];  // 2 x 32 KB
    __shared__ __align__(16) float xls[4096];               // 16 KB
    __shared__ __align__(16) float tsc[8 * 320];            // 10 KB per-wave transpose scratch

    const int tid = threadIdx.x, lane = tid & 63, w = tid >> 6;
    const int b = blockIdx.x;
    const int g = 2 * (b & 7) + (b >> 7);
    const int s = (b >> 3) & 15;
    const int m0 = g * 2048;
    const int l15 = lane & 15, lg = lane >> 4;
    const int q = l15 & 3, a = l15 >> 2;
    const int ct = w;
    const int hid = s * 32 + ct * 4 + a;
    float* const ts = tsc + w * 320;

    s16x8 bw[16];
    #pragma unroll
    for (int ks = 0; ks < 16; ++ks)
        bw[ks] = ((const s16x8*)PW1)[((s * 8 + ct) * 16 + ks) * 64 + lane];

    float b1v[4], wiA[4], wiB[4];
    #pragma unroll
    for (int k = 0; k < 4; ++k) {
        int gc = k * 512 + hid;
        b1v[k] = b1[gc];
        wiA[k] = w_ih0[gc * 2 + 0];
        wiB[k] = w_ih0[gc * 2 + 1];
    }
    float bo0 = b_out[0], bo1 = b_out[1];

    // ---- reduce prev-step partials -> xls; write out[:,t-1] ----
    if (t == 0) {
        #pragma unroll
        for (int i = 0; i < 8; ++i) xls[tid * 8 + i] = 0.0f;
    } else {
        f32x4 s0 = {0.f,0.f,0.f,0.f}, s1 = {0.f,0.f,0.f,0.f};
        #pragma unroll 1
        for (int ss = 0; ss < 16; ++ss) {
            const float* p = pp + (((size_t)(g * 16 + ss)) << 12) + tid * 8;
            s0 += *(const f32x4*)p;
            s1 += *(const f32x4*)(p + 4);
        }
        s0[0] += bo0; s0[1] += bo1; s0[2] += bo0; s0[3] += bo1;
        s1[0] += bo0; s1[1] += bo1; s1[2] += bo0; s1[3] += bo1;
        *(f32x4*)(xls + tid * 8) = s0;
        *(f32x4*)(xls + tid * 8 + 4) = s1;
        if (s == 0) {
            float* ob = outp + (size_t)(m0 + tid * 4) * (2 * NSTEP) + (t - 1) * 2;
            *(float2*)(ob)             = make_float2(s0[0], s0[1]);
            *(float2*)(ob + 2 * NSTEP) = make_float2(s0[2], s0[3]);
            *(float2*)(ob + 4 * NSTEP) = make_float2(s1[0], s1[1]);
            *(float2*)(ob + 6 * NSTEP) = make_float2(s1[2], s1[3]);
        }
    }

    const int st_l15 = tid & 15, st_lg = (tid >> 4) & 3, st_rh = (tid >> 6) & 1, st_kq = tid >> 7;
    const int st_grow = st_rh * 16 + st_l15;

    // prologue: stage chunk 0 into buf0; load chunk 1 into nv; prefetch c(0)
    uint4 nv[4];
    #pragma unroll
    for (int p = 0; p < 4; ++p) {
        int ks = p * 4 + st_kq;
        uint4 v = *(const uint4*)(h1R + (size_t)(m0 + st_grow) * HID + ks * 32 + st_lg * 8);
        *(uint4*)((char*)Ab + p * 8192 + tid * 16) = v;
    }
    #pragma unroll
    for (int p = 0; p < 4; ++p) {
        int ks = p * 4 + st_kq;
        nv[p] = *(const uint4*)(h1R + (size_t)(m0 + 32 + st_grow) * HID + ks * 32 + st_lg * 8);
    }
    unsigned short cpr0 = c1s[(size_t)(m0 + lg * 4 + q) * HID + hid];
    unsigned short cpr1 = c1s[(size_t)(m0 + 16 + lg * 4 + q) * HID + hid];
    __syncthreads();

    #pragma unroll 1
    for (int ch = 0; ch < 64; ++ch) {
        if (ch < 63) {
            char* AbW = (char*)Ab + ((ch + 1) & 1) * 32768;
            #pragma unroll
            for (int p = 0; p < 4; ++p)
                *(uint4*)(AbW + p * 8192 + tid * 16) = nv[p];
        }
        if (ch < 62) {
            #pragma unroll
            for (int p = 0; p < 4; ++p) {
                int ks = p * 4 + st_kq;
                nv[p] = *(const uint4*)(h1R + (size_t)(m0 + (ch + 2) * 32 + st_grow) * HID + ks * 32 + st_lg * 8);
            }
        }
        unsigned short cnx0 = 0, cnx1 = 0;
        if (ch < 63) {
            cnx0 = c1s[(size_t)(m0 + (ch + 1) * 32 + lg * 4 + q) * HID + hid];
            cnx1 = c1s[(size_t)(m0 + (ch + 1) * 32 + 16 + lg * 4 + q) * HID + hid];
        }

        const char* AbR = (const char*)Ab + (ch & 1) * 32768;
        // 4 independent MFMA chains (2 rh x 2 K-halves)
        f32x4 a0A = {0.f,0.f,0.f,0.f}, a0B = {0.f,0.f,0.f,0.f};
        f32x4 a1A = {0.f,0.f,0.f,0.f}, a1B = {0.f,0.f,0.f,0.f};
        #pragma unroll
        for (int ksl = 0; ksl < 8; ++ksl) {
            s16x8 x0 = *(const s16x8*)(AbR + ksl * 2048 + lane * 16);
            s16x8 x1 = *(const s16x8*)(AbR + ksl * 2048 + 1024 + lane * 16);
            a0A = __builtin_amdgcn_mfma_f32_16x16x32_bf16(x0, bw[ksl], a0A, 0, 0, 0);
            a1A = __builtin_amdgcn_mfma_f32_16x16x32_bf16(x1, bw[ksl], a1A, 0, 0, 0);
        }
        #pragma unroll
        for (int ksl = 8; ksl < 16; ++ksl) {
            s16x8 x0 = *(const s16x8*)(AbR + ksl * 2048 + lane * 16);
            s16x8 x1 = *(const s16x8*)(AbR + ksl * 2048 + 1024 + lane * 16);
            a0B = __builtin_amdgcn_mfma_f32_16x16x32_bf16(x0, bw[ksl], a0B, 0, 0, 0);
            a1B = __builtin_amdgcn_mfma_f32_16x16x32_bf16(x1, bw[ksl], a1B, 0, 0, 0);
        }
        f32x4 acS0 = a0A + a0B, acS1 = a1A + a1B;

        #pragma unroll
        for (int rh = 0; rh < 2; ++rh) {
            f32x4 ac = rh ? acS1 : acS0;
            // per-wave LDS transpose: ts[row*20 + col] = D[row][col]
            #pragma unroll
            for (int r = 0; r < 4; ++r)
                ts[(lg * 4 + r) * 20 + l15] = ac[r];
            // read gates 0..3 of unit a at row lg*4+q (in-order DS pipe: no barrier)
            f32x4 gq = *(const f32x4*)(ts + (lg * 4 + q) * 20 + a * 4);

            int grow = ch * 32 + rh * 16 + lg * 4 + q;
            float2 xv = *(const float2*)(xls + grow * 2);
            float iv = sigm(gq[0] + b1v[0] + xv.x * wiA[0] + xv.y * wiB[0]);
            float fv = sigm(gq[1] + b1v[1] + xv.x * wiA[1] + xv.y * wiB[1]);
            float gv = tanh_(gq[2] + b1v[2] + xv.x * wiA[2] + xv.y * wiB[2]);
            float ov = sigm(gq[3] + b1v[3] + xv.x * wiA[3] + xv.y * wiB[3]);
            float cold = bf2f(rh ? cpr1 : cpr0);
            float cn = fv * cold + iv * gv;
            float hn = ov * tanh_(cn);
            size_t cix = (size_t)(m0 + grow) * HID + hid;
            c1s[cix] = f2bf(cn);
            h1W[cix] = f2bf(hn);
        }
        cpr0 = cnx0; cpr1 = cnx1;
        __syncthreads();
    }
}

// ---------------- layer-2: per-wave full-K (K=1024), LDS-scratch transpose, 1 barrier/chunk ----------------
__global__ __launch_bounds__(TPB, 2) void l2_kernel(
    const unsigned short* __restrict__ h1C, const unsigned short* __restrict__ h2R,
    unsigned short* __restrict__ h2W, unsigned short* __restrict__ c2s,
    float* __restrict__ pp,
    const unsigned short* __restrict__ PW2, const float* __restrict__ b2,
    const float* __restrict__ w_out)
{
    __shared__ __align__(16) unsigned short Ab[2 * 32768];  // 2 x 64 KB
    __shared__ __align__(16) float pl[2][32][2][9];         // 4.5 KB padded partials
    __shared__ __align__(16) float tsc[8 * 320];            // 10 KB

    const int tid = threadIdx.x, lane = tid & 63, w = tid >> 6;
    const int b = blockIdx.x;
    const int g = 2 * (b & 7) + (b >> 7);
    const int s = (b >> 3) & 15;
    const int m0 = g * 2048;
    const int l15 = lane & 15, lg = lane >> 4;
    const int q = l15 & 3, a = l15 >> 2;
    const int ct = w;
    const int hid = s * 32 + ct * 4 + a;
    float* const ts = tsc + w * 320;

    s16x8 bw[32];
    #pragma unroll
    for (int ks = 0; ks < 32; ++ks)
        bw[ks] = ((const s16x8*)PW2)[((s * 8 + ct) * 32 + ks) * 64 + lane];

    float b2v[4];
    #pragma unroll
    for (int k = 0; k < 4; ++k) b2v[k] = b2[k * 512 + hid];
    const float wo0 = w_out[hid], wo1 = w_out[512 + hid];

    const int st_l15 = tid & 15, st_lg = (tid >> 4) & 3, st_rh = (tid >> 6) & 1, st_kq = tid >> 7;
    const int st_grow = st_rh * 16 + st_l15;

    uint4 nv[8];
    #pragma unroll
    for (int p = 0; p < 8; ++p) {
        int ks = p * 4 + st_kq;
        const unsigned short* src = (ks < 16) ? h1C : h2R;
        int kel = (ks < 16) ? ks : (ks - 16);
        uint4 v = *(const uint4*)(src + (size_t)(m0 + st_grow) * HID + kel * 32 + st_lg * 8);
        *(uint4*)((char*)Ab + p * 8192 + tid * 16) = v;
    }
    #pragma unroll
    for (int p = 0; p < 8; ++p) {
        int ks = p * 4 + st_kq;
        const unsigned short* src = (ks < 16) ? h1C : h2R;
        int kel = (ks < 16) ? ks : (ks - 16);
        nv[p] = *(const uint4*)(src + (size_t)(m0 + 32 + st_grow) * HID + kel * 32 + st_lg * 8);
    }
    unsigned short cpr0 = c2s[(size_t)(m0 + lg * 4 + q) * HID + hid];
    unsigned short cpr1 = c2s[(size_t)(m0 + 16 + lg * 4 + q) * HID + hid];
    __syncthreads();

    #pragma unroll 1
    for (int ch = 0; ch < 64; ++ch) {
        if (ch < 63) {
            char* AbW = (char*)Ab + ((ch + 1) & 1) * 65536;
            #pragma unroll
            for (int p = 0; p < 8; ++p)
                *(uint4*)(AbW + p * 8192 + tid * 16) = nv[p];
        }
        if (ch < 62) {
            #pragma unroll
            for (int p = 0; p < 8; ++p) {
                int ks = p * 4 + st_kq;
                const unsigned short* src = (ks < 16) ? h1C : h2R;
                int kel = (ks < 16) ? ks : (ks - 16);
                nv[p] = *(const uint4*)(src + (size_t)(m0 + (ch + 2) * 32 + st_grow) * HID + kel * 32 + st_lg * 8);
            }
        }
        unsigned short cnx0 = 0, cnx1 = 0;
        if (ch < 63) {
            cnx0 = c2s[(size_t)(m0 + (ch + 1) * 32 + lg * 4 + q) * HID + hid];
            cnx1 = c2s[(size_t)(m0 + (ch + 1) * 32 + 16 + lg * 4 + q) * HID + hid];
        }

        const char* AbR = (const char*)Ab + (ch & 1) * 65536;
        f32x4 a0A = {0.f,0.f,0.f,0.f}, a0B = {0.f,0.f,0.f,0.f};
        f32x4 a1A = {0.f,0.f,0.f,0.f}, a1B = {0.f,0.f,0.f,0.f};
        #pragma unroll
        for (int ksl = 0; ksl < 16; ++ksl) {
            s16x8 x0 = *(const s16x8*)(AbR + ksl * 2048 + lane * 16);
            s16x8 x1 = *(const s16x8*)(AbR + ksl * 2048 + 1024 + lane * 16);
            a0A = __builtin_amdgcn_mfma_f32_16x16x32_bf16(x0, bw[ksl], a0A, 0, 0, 0);
            a1A = __builtin_amdgcn_mfma_f32_16x16x32_bf16(x1, bw[ksl], a1A, 0, 0, 0);
        }
        #pragma unroll
        for (int ksl = 16; ksl < 32; ++ksl) {
            s16x8 x0 = *(const s16x8*)(AbR + ksl * 2048 + lane * 16);
            s16x8 x1 = *(const s16x8*)(AbR + ksl * 2048 + 1024 + lane * 16);
            a0B = __builtin_amdgcn_mfma_f32_16x16x32_bf16(x0, bw[ksl], a0B, 0, 0, 0);
            a1B = __builtin_amdgcn_mfma_f32_16x16x32_bf16(x1, bw[ksl], a1B, 0, 0, 0);
        }
        f32x4 acS0 = a0A + a0B, acS1 = a1A + a1B;

        #pragma unroll
        for (int rh = 0; rh < 2; ++rh) {
            f32x4 ac = rh ? acS1 : acS0;
            #pragma unroll
            for (int r = 0; r < 4; ++r)
                ts[(lg * 4 + r) * 20 + l15] = ac[r];
            f32x4 gq = *(const f32x4*)(ts + (lg * 4 + q) * 20 + a * 4);

            int rloc = rh * 16 + lg * 4 + q;
            int grow = ch * 32 + rloc;
            float iv = sigm(gq[0] + b2v[0]);
            float fv = sigm(gq[1] + b2v[1]);
            float gv = tanh_(gq[2] + b2v[2]);
            float ov = sigm(gq[3] + b2v[3]);
            float cold = bf2f(rh ? cpr1 : cpr0);
            float cn = fv * cold + iv * gv;
            float hn = ov * tanh_(cn);
            size_t cix = (size_t)(m0 + grow) * HID + hid;
            c2s[cix] = f2bf(cn);
            h2W[cix] = f2bf(hn);
            // output partial: reduce over the 4 units (lane bits 2,3)
            float p0 = hn * wo0, p1 = hn * wo1;
            p0 += __shfl_xor(p0, 4); p0 += __shfl_xor(p0, 8);
            p1 += __shfl_xor(p1, 4); p1 += __shfl_xor(p1, 8);
            if (a == 0) {
                pl[ch & 1][rloc][0][ct] = p0;
                pl[ch & 1][rloc][1][ct] = p1;
            }
        }
        // consume previous chunk's partials (after prior barrier; no extra barrier)
        if (ch > 0 && tid < 64) {
            int row = tid >> 1, j = tid & 1;
            const float* pr = &pl[(ch - 1) & 1][row][j][0];
            float sum = pr[0] + pr[1] + pr[2] + pr[3] + pr[4] + pr[5] + pr[6] + pr[7];
            pp[((size_t)(g * 16 + s)) * 4096 + (size_t)((ch - 1) * 32 + row) * 2 + j] = sum;
        }
        cpr0 = cnx0; cpr1 = cnx1;
        __syncthreads();
    }
    if (tid < 64) {
        int row = tid >> 1, j = tid & 1;
        const float* pr = &pl[1][row][j][0];
        float sum = pr[0] + pr[1] + pr[2] + pr[3] + pr[4] + pr[5] + pr[6] + pr[7];
        pp[((size_t)(g * 16 + s)) * 4096 + (size_t)(63 * 32 + row) * 2 + j] = sum;
    }
}

// ---------------- final-step output ----------------
__global__ void tail_kernel(const float* __restrict__ pp, const float* __restrict__ b_out,
                            float* __restrict__ outp)
{
    int i = blockIdx.x * 256 + threadIdx.x;
    if (i < 65536) {
        int m = i >> 1, j = i & 1;
        int g = m >> 11;
        int idx = (m & 2047) * 2 + j;
        float sum = b_out[j];
        #pragma unroll 1
        for (int s = 0; s < 16; ++s)
            sum += pp[(((size_t)(g * 16 + s)) << 12) + idx];
        outp[(size_t)m * (2 * NSTEP) + (NSTEP - 1) * 2 + j] = sum;
    }
}

extern "C" void kernel_launch(void* const* d_in, const int* in_sizes, int n_in,
                              void* d_out, int out_size, void* d_ws, size_t ws_size,
                              hipStream_t stream)
{
    (void)in_sizes; (void)n_in; (void)out_size; (void)ws_size;
    const float* h        = (const float*)d_in[0];
    const float* w_init_h = (const float*)d_in[1];
    const float* b_init_h = (const float*)d_in[2];
    const float* w_init_c = (const float*)d_in[3];
    const float* b_init_c = (const float*)d_in[4];
    const float* w_ih0    = (const float*)d_in[5];
    const float* w_hh0    = (const float*)d_in[6];
    const float* b_ih0    = (const float*)d_in[7];
    const float* b_hh0    = (const float*)d_in[8];
    const float* w_ih1    = (const float*)d_in[9];
    const float* w_hh1    = (const float*)d_in[10];
    const float* b_ih1    = (const float*)d_in[11];
    const float* b_hh1    = (const float*)d_in[12];
    const float* w_out    = (const float*)d_in[13];
    const float* b_out    = (const float*)d_in[14];
    float* out = (float*)d_out;

    char* ws = (char*)d_ws;
    unsigned short* h1s[2] = { (unsigned short*)(ws + 0),
                               (unsigned short*)(ws + 33554432) };
    unsigned short* h2s[2] = { (unsigned short*)(ws + 67108864),
                               (unsigned short*)(ws + 100663296) };
    unsigned short* c1s = (unsigned short*)(ws + 134217728);
    unsigned short* c2s = (unsigned short*)(ws + 167772160);
    float* pp           = (float*)(ws + 201326592);   // 4 MB
    unsigned short* PW1 = (unsigned short*)(ws + 205520896);
    unsigned short* PW2 = (unsigned short*)(ws + 207618048);
    unsigned short* PI  = (unsigned short*)(ws + 211812352);
    float* b1 = (float*)(ws + 212860928);
    float* b2 = (float*)(ws + 212869120);

    pack_kernel<<<14352, 256, 0, stream>>>(w_hh0, w_ih1, w_hh1, w_init_h, w_init_c,
                                           b_ih0, b_hh0, b_ih1, b_hh1, PW1, PW2, PI, b1, b2);
    init_kernel<<<32768 / BMI, TPB, 0, stream>>>(h, PI, b_init_h, b_init_c,
                                                 h1s[1], h2s[1], c1s, c2s);
    for (int t = 0; t < NSTEP; ++t) {
        const unsigned short* h1R = h1s[(t + 1) & 1];
        unsigned short* h1W = h1s[t & 1];
        const unsigned short* h2R = h2s[(t + 1) & 1];
        unsigned short* h2W = h2s[t & 1];
        l1_kernel<<<256, TPB, 0, stream>>>(h1R, h1W, c1s, pp, out, PW1, b1, w_ih0, b_out, t);
        l2_kernel<<<256, TPB, 0, stream>>>(h1W, h2R, h2W, c2s, pp, PW2, b2, w_out);
    }
    tail_kernel<<<256, 256, 0, stream>>>(pp, b_out, out);
}